// Round 1
// baseline (588.886 us; speedup 1.0000x reference)
//
#include <hip/hip_runtime.h>
#include <hip/hip_bf16.h>
#include <stdint.h>

#define EMB 1024
#define HID 1024
#define NE 16
#define NTOK 8192
#define NSLOT (NTOK * 2)
#define BM 128
#define BN 128
#define BK 32
#define LDT 40   // padded LDS row stride (bf16 elems): 80 B, breaks stride-64B bank conflict

typedef __bf16 bf16;
typedef __bf16 bf16x8 __attribute__((ext_vector_type(8)));
typedef __bf16 bf16x4 __attribute__((ext_vector_type(4)));
typedef float f32x4 __attribute__((ext_vector_type(4)));

// ---------------- weight transpose + fp32->bf16 ----------------
// src: [16][1024][1024] fp32 row-major; dst: per-matrix transpose, bf16.
__global__ void transpose_cvt(const float* __restrict__ src, bf16* __restrict__ dst) {
  __shared__ float tile[32][33];
  int z = blockIdx.z;
  int x0 = blockIdx.x << 5, y0 = blockIdx.y << 5;
  const float* s = src + (size_t)z * EMB * HID;
  bf16* d = dst + (size_t)z * EMB * HID;
  int tx = threadIdx.x, ty = threadIdx.y;
#pragma unroll
  for (int i = 0; i < 32; i += 8)
    tile[ty + i][tx] = s[(size_t)(y0 + ty + i) * 1024 + x0 + tx];
  __syncthreads();
#pragma unroll
  for (int i = 0; i < 32; i += 8)
    d[(size_t)(x0 + ty + i) * 1024 + y0 + tx] = (bf16)tile[tx][ty + i];
}

// ---------------- x fp32 -> bf16 ----------------
__global__ void cvt_x(const float4* __restrict__ x, bf16x4* __restrict__ xb) {
  int i = blockIdx.x * blockDim.x + threadIdx.x;
  float4 v = x[i];
  bf16x4 o;
  o[0] = (bf16)v.x; o[1] = (bf16)v.y; o[2] = (bf16)v.z; o[3] = (bf16)v.w;
  xb[i] = o;
}

// ---------------- router: fp32 logits, softmax, top-2 ----------------
__global__ void router_k(const float* __restrict__ x, const float* __restrict__ wg,
                         int* __restrict__ tokexp, float* __restrict__ tokgate,
                         int* __restrict__ cnt) {
  int t = (int)((blockIdx.x * blockDim.x + threadIdx.x) >> 6);
  int lane = threadIdx.x & 63;
  const float* xr = x + (size_t)t * EMB;
  float acc[NE];
#pragma unroll
  for (int e = 0; e < NE; e++) acc[e] = 0.f;
  int d0 = lane * 16;
  for (int i = 0; i < 16; i++) {
    float xi = xr[d0 + i];
    const float* wr = wg + (size_t)(d0 + i) * NE;
#pragma unroll
    for (int e = 0; e < NE; e++) acc[e] += xi * wr[e];
  }
#pragma unroll
  for (int e = 0; e < NE; e++) {
    for (int s = 32; s > 0; s >>= 1) acc[e] += __shfl_xor(acc[e], s);
  }
  if (lane == 0) {
    float m = acc[0];
#pragma unroll
    for (int e = 1; e < NE; e++) m = fmaxf(m, acc[e]);
    float p[NE]; float sum = 0.f;
#pragma unroll
    for (int e = 0; e < NE; e++) { p[e] = __expf(acc[e] - m); sum += p[e]; }
    float inv = 1.f / sum;
#pragma unroll
    for (int e = 0; e < NE; e++) p[e] *= inv;
    int i1 = 0;
#pragma unroll
    for (int e = 1; e < NE; e++) if (p[e] > p[i1]) i1 = e;   // first-occurrence max
    int i2 = (i1 == 0) ? 1 : 0;
#pragma unroll
    for (int e = 0; e < NE; e++) if (e != i1 && p[e] > p[i2]) i2 = e;
    tokexp[2 * t] = i1; tokexp[2 * t + 1] = i2;
    tokgate[2 * t] = p[i1]; tokgate[2 * t + 1] = p[i2];
    atomicAdd(&cnt[i1], 1); atomicAdd(&cnt[i2], 1);
  }
}

// ---------------- tiny 16-wide exclusive scan ----------------
__global__ void scan_k(const int* __restrict__ cnt, int* __restrict__ eoff,
                       int* __restrict__ cursor) {
  if (threadIdx.x == 0) {
    int s = 0;
    for (int e = 0; e < NE; e++) { eoff[e] = s; cursor[e] = s; s += cnt[e]; }
  }
}

// ---------------- slot -> compact row assignment ----------------
__global__ void assign_k(const int* __restrict__ tokexp, const float* __restrict__ tokgate,
                         int* __restrict__ cursor, int* __restrict__ rowtok,
                         float* __restrict__ rowgate) {
  int s = blockIdx.x * blockDim.x + threadIdx.x;
  int e = tokexp[s];
  int pos = atomicAdd(&cursor[e], 1);
  rowtok[pos] = s >> 1;
  rowgate[pos] = tokgate[s];
}

// ---------------- GEMM1: H = silu(X@W1) * (X@W2), gathered rows ----------------
__launch_bounds__(256, 2)
__global__ void gemm1_k(const bf16* __restrict__ xb, const bf16* __restrict__ w1t,
                        const bf16* __restrict__ w2t, const int* __restrict__ cnt,
                        const int* __restrict__ eoff, const int* __restrict__ rowtok,
                        bf16* __restrict__ H) {
  int e = blockIdx.z;
  int n_e = cnt[e];
  int m0 = blockIdx.y * BM;
  if (m0 >= n_e) return;
  int n0 = blockIdx.x * BN;
  int base = eoff[e];

  __shared__ __align__(16) bf16 sA[BM * LDT];
  __shared__ __align__(16) bf16 sB1[BN * LDT];
  __shared__ __align__(16) bf16 sB2[BN * LDT];

  int tid = threadIdx.x;
  int lane = tid & 63;
  int wv = tid >> 6;
  int wr = (wv >> 1) << 6;
  int wc = (wv & 1) << 6;

  int srow = tid >> 2;          // 0..63
  int kc = (tid & 3) << 3;      // 0,8,16,24 (bf16 elems)

  const bf16* aptr[2];
#pragma unroll
  for (int p = 0; p < 2; p++) {
    int gi = base + m0 + srow + (p << 6);
    gi = gi < NSLOT ? gi : NSLOT - 1;   // clamp: garbage rows never stored
    aptr[p] = xb + (size_t)rowtok[gi] * EMB + kc;
  }
  const bf16* b1p = w1t + ((size_t)e * HID + n0 + srow) * EMB + kc;
  const bf16* b2p = w2t + ((size_t)e * HID + n0 + srow) * EMB + kc;

  f32x4 acc1[4][4] = {};
  f32x4 acc2[4][4] = {};

  for (int k0 = 0; k0 < EMB; k0 += BK) {
    uint4 a0 = *(const uint4*)(aptr[0] + k0);
    uint4 a1 = *(const uint4*)(aptr[1] + k0);
    uint4 b10 = *(const uint4*)(b1p + k0);
    uint4 b11 = *(const uint4*)(b1p + (size_t)64 * EMB + k0);
    uint4 b20 = *(const uint4*)(b2p + k0);
    uint4 b21 = *(const uint4*)(b2p + (size_t)64 * EMB + k0);
    *(uint4*)&sA[srow * LDT + kc] = a0;
    *(uint4*)&sA[(srow + 64) * LDT + kc] = a1;
    *(uint4*)&sB1[srow * LDT + kc] = b10;
    *(uint4*)&sB1[(srow + 64) * LDT + kc] = b11;
    *(uint4*)&sB2[srow * LDT + kc] = b20;
    *(uint4*)&sB2[(srow + 64) * LDT + kc] = b21;
    __syncthreads();

    bf16x8 af[4], b1f[4], b2f[4];
    int ra = (wr + (lane & 15)) * LDT + ((lane >> 4) << 3);
    int rb = (wc + (lane & 15)) * LDT + ((lane >> 4) << 3);
#pragma unroll
    for (int m = 0; m < 4; m++) af[m] = *(const bf16x8*)&sA[ra + m * 16 * LDT];
#pragma unroll
    for (int n = 0; n < 4; n++) {
      b1f[n] = *(const bf16x8*)&sB1[rb + n * 16 * LDT];
      b2f[n] = *(const bf16x8*)&sB2[rb + n * 16 * LDT];
    }
#pragma unroll
    for (int m = 0; m < 4; m++)
#pragma unroll
      for (int n = 0; n < 4; n++) {
        acc1[m][n] = __builtin_amdgcn_mfma_f32_16x16x32_bf16(af[m], b1f[n], acc1[m][n], 0, 0, 0);
        acc2[m][n] = __builtin_amdgcn_mfma_f32_16x16x32_bf16(af[m], b2f[n], acc2[m][n], 0, 0, 0);
      }
    __syncthreads();
  }

  // epilogue: silu(c1)*c2 -> bf16 H.  D frag: col=lane&15, row=4*(lane>>4)+b
  int rf = wr + ((lane >> 4) << 2);
  int cf = n0 + wc + (lane & 15);
#pragma unroll
  for (int m = 0; m < 4; m++) {
#pragma unroll
    for (int n = 0; n < 4; n++) {
#pragma unroll
      for (int b = 0; b < 4; b++) {
        int gr = m0 + rf + m * 16 + b;
        if (gr < n_e) {
          float c1 = acc1[m][n][b];
          float c2 = acc2[m][n][b];
          float h = c1 * c2 / (1.f + __expf(-c1));
          H[(size_t)(base + gr) * HID + cf + n * 16] = (bf16)h;
        }
      }
    }
  }
}

// ---------------- GEMM2: out[tok] += gate * (H @ Wc) ----------------
__launch_bounds__(256, 2)
__global__ void gemm2_k(const bf16* __restrict__ H, const bf16* __restrict__ wct,
                        const int* __restrict__ cnt, const int* __restrict__ eoff,
                        const int* __restrict__ rowtok, const float* __restrict__ rowgate,
                        float* __restrict__ out) {
  int e = blockIdx.z;
  int n_e = cnt[e];
  int m0 = blockIdx.y * BM;
  if (m0 >= n_e) return;
  int n0 = blockIdx.x * BN;
  int base = eoff[e];

  __shared__ __align__(16) bf16 sA[BM * LDT];
  __shared__ __align__(16) bf16 sB[BN * LDT];

  int tid = threadIdx.x;
  int lane = tid & 63;
  int wv = tid >> 6;
  int wr = (wv >> 1) << 6;
  int wc = (wv & 1) << 6;

  int srow = tid >> 2;
  int kc = (tid & 3) << 3;

  const bf16* ap[2];
#pragma unroll
  for (int p = 0; p < 2; p++) {
    int gi = base + m0 + srow + (p << 6);
    gi = gi < NSLOT ? gi : NSLOT - 1;
    ap[p] = H + (size_t)gi * HID + kc;
  }
  const bf16* bp = wct + ((size_t)e * EMB + n0 + srow) * HID + kc;

  f32x4 acc[4][4] = {};

  for (int k0 = 0; k0 < HID; k0 += BK) {
    uint4 a0 = *(const uint4*)(ap[0] + k0);
    uint4 a1 = *(const uint4*)(ap[1] + k0);
    uint4 b0 = *(const uint4*)(bp + k0);
    uint4 b1 = *(const uint4*)(bp + (size_t)64 * HID + k0);
    *(uint4*)&sA[srow * LDT + kc] = a0;
    *(uint4*)&sA[(srow + 64) * LDT + kc] = a1;
    *(uint4*)&sB[srow * LDT + kc] = b0;
    *(uint4*)&sB[(srow + 64) * LDT + kc] = b1;
    __syncthreads();

    bf16x8 af[4], bfr[4];
    int ra = (wr + (lane & 15)) * LDT + ((lane >> 4) << 3);
    int rb = (wc + (lane & 15)) * LDT + ((lane >> 4) << 3);
#pragma unroll
    for (int m = 0; m < 4; m++) af[m] = *(const bf16x8*)&sA[ra + m * 16 * LDT];
#pragma unroll
    for (int n = 0; n < 4; n++) bfr[n] = *(const bf16x8*)&sB[rb + n * 16 * LDT];
#pragma unroll
    for (int m = 0; m < 4; m++)
#pragma unroll
      for (int n = 0; n < 4; n++)
        acc[m][n] = __builtin_amdgcn_mfma_f32_16x16x32_bf16(af[m], bfr[n], acc[m][n], 0, 0, 0);
    __syncthreads();
  }

  int rf = wr + ((lane >> 4) << 2);
  int cf = n0 + wc + (lane & 15);
#pragma unroll
  for (int m = 0; m < 4; m++) {
#pragma unroll
    for (int b = 0; b < 4; b++) {
      int gr = m0 + rf + m * 16 + b;
      if (gr < n_e) {
        int idx = base + gr;
        int tok = rowtok[idx];
        float g = rowgate[idx];
        float* orow = out + (size_t)tok * EMB + cf;
#pragma unroll
        for (int n = 0; n < 4; n++)
          atomicAdd(orow + n * 16, g * acc[m][n][b]);
      }
    }
  }
}

extern "C" void kernel_launch(void* const* d_in, const int* in_sizes, int n_in,
                              void* d_out, int out_size, void* d_ws, size_t ws_size,
                              hipStream_t stream) {
  const float* x  = (const float*)d_in[0];
  const float* wg = (const float*)d_in[1];
  const float* w1 = (const float*)d_in[2];
  const float* w2 = (const float*)d_in[3];
  const float* wc = (const float*)d_in[4];
  float* out = (float*)d_out;

  const size_t WELEM = (size_t)NE * EMB * HID;
  bf16* w1t  = (bf16*)d_ws;                 // [E][HID][EMB] bf16 (W1^T per expert)
  bf16* w2t  = w1t + WELEM;                 // [E][HID][EMB]
  bf16* wct  = w2t + WELEM;                 // [E][EMB][HID] (Wc^T per expert)
  bf16* xb   = wct + WELEM;                 // [NTOK][EMB] bf16
  bf16* Hbuf = xb + (size_t)NTOK * EMB;     // [NSLOT][HID] bf16
  int* cnt    = (int*)(Hbuf + (size_t)NSLOT * HID);
  int* eoff   = cnt + 16;
  int* cursor = eoff + 16;
  int* tokexp = cursor + 16;                // [NSLOT]
  float* tokgate = (float*)(tokexp + NSLOT);
  int* rowtok    = (int*)(tokgate + NSLOT);
  float* rowgate = (float*)(rowtok + NSLOT);
  // total ws use: ~151.3 MB

  hipMemsetAsync(cnt, 0, 16 * sizeof(int), stream);
  hipMemsetAsync(out, 0, (size_t)out_size * sizeof(float), stream);

  dim3 tb(32, 8), tg(32, 32, NE);
  transpose_cvt<<<tg, tb, 0, stream>>>(w1, w1t);
  transpose_cvt<<<tg, tb, 0, stream>>>(w2, w2t);
  transpose_cvt<<<tg, tb, 0, stream>>>(wc, wct);
  cvt_x<<<(NTOK * EMB / 4) / 256, 256, 0, stream>>>((const float4*)x, (bf16x4*)xb);
  router_k<<<NTOK / 4, 256, 0, stream>>>(x, wg, tokexp, tokgate, cnt);
  scan_k<<<1, 64, 0, stream>>>(cnt, eoff, cursor);
  assign_k<<<NSLOT / 256, 256, 0, stream>>>(tokexp, tokgate, cursor, rowtok, rowgate);
  dim3 g1(HID / BN, NTOK / BM, NE);
  gemm1_k<<<g1, 256, 0, stream>>>(xb, w1t, w2t, cnt, eoff, rowtok, Hbuf);
  dim3 g2(EMB / BN, NTOK / BM, NE);
  gemm2_k<<<g2, 256, 0, stream>>>(Hbuf, wct, cnt, eoff, rowtok, rowgate, out);
}

// Round 2
// 559.155 us; speedup vs baseline: 1.0532x; 1.0532x over previous
//
#include <hip/hip_runtime.h>
#include <hip/hip_bf16.h>
#include <stdint.h>

#define EMB 1024
#define HID 1024
#define NE 16
#define NTOK 8192
#define NSLOT (NTOK * 2)
#define BM 128
#define BN 128
#define BK 32
#define LDT 40   // padded LDS row stride (bf16 elems): 80 B, breaks stride-64B bank conflict

typedef __bf16 bf16;
typedef __bf16 bf16x8 __attribute__((ext_vector_type(8)));
typedef __bf16 bf16x4 __attribute__((ext_vector_type(4)));
typedef float f32x4 __attribute__((ext_vector_type(4)));

// ---------------- weight transpose + fp32->bf16 ----------------
__global__ void transpose_cvt(const float* __restrict__ src, bf16* __restrict__ dst) {
  __shared__ float tile[32][33];
  int z = blockIdx.z;
  int x0 = blockIdx.x << 5, y0 = blockIdx.y << 5;
  const float* s = src + (size_t)z * EMB * HID;
  bf16* d = dst + (size_t)z * EMB * HID;
  int tx = threadIdx.x, ty = threadIdx.y;
#pragma unroll
  for (int i = 0; i < 32; i += 8)
    tile[ty + i][tx] = s[(size_t)(y0 + ty + i) * 1024 + x0 + tx];
  __syncthreads();
#pragma unroll
  for (int i = 0; i < 32; i += 8)
    d[(size_t)(x0 + ty + i) * 1024 + y0 + tx] = (bf16)tile[tx][ty + i];
}

// ---------------- w_gate [1024][16] -> wgT [16][1024] (fp32, 64KB, one-time) ----------
__global__ void wgT_k(const float* __restrict__ wg, float* __restrict__ wgT) {
  int f = blockIdx.x * 256 + threadIdx.x;   // 0..16383, coalesced read
  int d = f >> 4, e = f & 15;
  wgT[e * 1024 + d] = wg[f];
}

// ---------------- router: coalesced, LDS-staged wgT, fused x->bf16 ----------------
// 512 threads = 8 waves = 8 tokens per block. LDS: wgT 16x1024 fp32 = 64KB.
__launch_bounds__(512)
__global__ void router_k(const float* __restrict__ x, const float* __restrict__ wgT,
                         bf16* __restrict__ xb,
                         int* __restrict__ tokexp, float* __restrict__ tokgate,
                         int* __restrict__ cnt) {
  __shared__ float wgs[NE * 1024];
  // stage wgT: 4096 float4s, 8 per thread, coalesced
  for (int i = threadIdx.x; i < 4096; i += 512)
    ((float4*)wgs)[i] = ((const float4*)wgT)[i];
  __syncthreads();

  int t = blockIdx.x * 8 + (threadIdx.x >> 6);
  int lane = threadIdx.x & 63;
  const float* xr = x + (size_t)t * EMB;

  float acc[NE];
#pragma unroll
  for (int e = 0; e < NE; e++) acc[e] = 0.f;

#pragma unroll
  for (int c = 0; c < 4; c++) {
    float4 xv = ((const float4*)xr)[c * 64 + lane];         // coalesced 16B/lane
    int dbase = c * 256 + lane * 4;
    // fused fp32->bf16 store of x
    bf16x4 o;
    o[0] = (bf16)xv.x; o[1] = (bf16)xv.y; o[2] = (bf16)xv.z; o[3] = (bf16)xv.w;
    *(bf16x4*)(xb + (size_t)t * EMB + dbase) = o;
#pragma unroll
    for (int e = 0; e < NE; e++) {
      float4 wv = *(const float4*)&wgs[e * 1024 + dbase];   // ds_read_b128, conflict-free
      acc[e] += xv.x * wv.x + xv.y * wv.y + xv.z * wv.z + xv.w * wv.w;
    }
  }
#pragma unroll
  for (int e = 0; e < NE; e++) {
#pragma unroll
    for (int s = 32; s > 0; s >>= 1) acc[e] += __shfl_xor(acc[e], s);
  }
  if (lane == 0) {
    float m = acc[0];
#pragma unroll
    for (int e = 1; e < NE; e++) m = fmaxf(m, acc[e]);
    float p[NE]; float sum = 0.f;
#pragma unroll
    for (int e = 0; e < NE; e++) { p[e] = __expf(acc[e] - m); sum += p[e]; }
    float inv = 1.f / sum;
#pragma unroll
    for (int e = 0; e < NE; e++) p[e] *= inv;
    int i1 = 0;
#pragma unroll
    for (int e = 1; e < NE; e++) if (p[e] > p[i1]) i1 = e;   // first-occurrence max
    int i2 = (i1 == 0) ? 1 : 0;
#pragma unroll
    for (int e = 0; e < NE; e++) if (e != i1 && p[e] > p[i2]) i2 = e;
    tokexp[2 * t] = i1; tokexp[2 * t + 1] = i2;
    tokgate[2 * t] = p[i1]; tokgate[2 * t + 1] = p[i2];
    atomicAdd(&cnt[i1], 1); atomicAdd(&cnt[i2], 1);
  }
}

// ---------------- tiny 16-wide exclusive scan ----------------
__global__ void scan_k(const int* __restrict__ cnt, int* __restrict__ eoff,
                       int* __restrict__ cursor) {
  if (threadIdx.x == 0) {
    int s = 0;
    for (int e = 0; e < NE; e++) { eoff[e] = s; cursor[e] = s; s += cnt[e]; }
  }
}

// ---------------- slot -> compact row assignment ----------------
__global__ void assign_k(const int* __restrict__ tokexp, const float* __restrict__ tokgate,
                         int* __restrict__ cursor, int* __restrict__ rowtok,
                         float* __restrict__ rowgate) {
  int s = blockIdx.x * blockDim.x + threadIdx.x;
  int e = tokexp[s];
  int pos = atomicAdd(&cursor[e], 1);
  rowtok[pos] = s >> 1;
  rowgate[pos] = tokgate[s];
}

// ---------------- GEMM1: H = silu(X@W1) * (X@W2), gathered rows ----------------
__launch_bounds__(256, 2)
__global__ void gemm1_k(const bf16* __restrict__ xb, const bf16* __restrict__ w1t,
                        const bf16* __restrict__ w2t, const int* __restrict__ cnt,
                        const int* __restrict__ eoff, const int* __restrict__ rowtok,
                        bf16* __restrict__ H) {
  int e = blockIdx.z;
  int n_e = cnt[e];
  int m0 = blockIdx.y * BM;
  if (m0 >= n_e) return;
  int n0 = blockIdx.x * BN;
  int base = eoff[e];

  __shared__ __align__(16) bf16 sA[BM * LDT];
  __shared__ __align__(16) bf16 sB1[BN * LDT];
  __shared__ __align__(16) bf16 sB2[BN * LDT];

  int tid = threadIdx.x;
  int lane = tid & 63;
  int wv = tid >> 6;
  int wr = (wv >> 1) << 6;
  int wc = (wv & 1) << 6;

  int srow = tid >> 2;          // 0..63
  int kc = (tid & 3) << 3;      // 0,8,16,24 (bf16 elems)

  const bf16* aptr[2];
#pragma unroll
  for (int p = 0; p < 2; p++) {
    int gi = base + m0 + srow + (p << 6);
    gi = gi < NSLOT ? gi : NSLOT - 1;   // clamp: garbage rows never stored
    aptr[p] = xb + (size_t)rowtok[gi] * EMB + kc;
  }
  const bf16* b1p = w1t + ((size_t)e * HID + n0 + srow) * EMB + kc;
  const bf16* b2p = w2t + ((size_t)e * HID + n0 + srow) * EMB + kc;

  f32x4 acc1[4][4] = {};
  f32x4 acc2[4][4] = {};

  for (int k0 = 0; k0 < EMB; k0 += BK) {
    uint4 a0 = *(const uint4*)(aptr[0] + k0);
    uint4 a1 = *(const uint4*)(aptr[1] + k0);
    uint4 b10 = *(const uint4*)(b1p + k0);
    uint4 b11 = *(const uint4*)(b1p + (size_t)64 * EMB + k0);
    uint4 b20 = *(const uint4*)(b2p + k0);
    uint4 b21 = *(const uint4*)(b2p + (size_t)64 * EMB + k0);
    *(uint4*)&sA[srow * LDT + kc] = a0;
    *(uint4*)&sA[(srow + 64) * LDT + kc] = a1;
    *(uint4*)&sB1[srow * LDT + kc] = b10;
    *(uint4*)&sB1[(srow + 64) * LDT + kc] = b11;
    *(uint4*)&sB2[srow * LDT + kc] = b20;
    *(uint4*)&sB2[(srow + 64) * LDT + kc] = b21;
    __syncthreads();

    bf16x8 af[4], b1f[4], b2f[4];
    int ra = (wr + (lane & 15)) * LDT + ((lane >> 4) << 3);
    int rb = (wc + (lane & 15)) * LDT + ((lane >> 4) << 3);
#pragma unroll
    for (int m = 0; m < 4; m++) af[m] = *(const bf16x8*)&sA[ra + m * 16 * LDT];
#pragma unroll
    for (int n = 0; n < 4; n++) {
      b1f[n] = *(const bf16x8*)&sB1[rb + n * 16 * LDT];
      b2f[n] = *(const bf16x8*)&sB2[rb + n * 16 * LDT];
    }
#pragma unroll
    for (int m = 0; m < 4; m++)
#pragma unroll
      for (int n = 0; n < 4; n++) {
        acc1[m][n] = __builtin_amdgcn_mfma_f32_16x16x32_bf16(af[m], b1f[n], acc1[m][n], 0, 0, 0);
        acc2[m][n] = __builtin_amdgcn_mfma_f32_16x16x32_bf16(af[m], b2f[n], acc2[m][n], 0, 0, 0);
      }
    __syncthreads();
  }

  // epilogue: silu(c1)*c2 -> bf16 H.  D frag: col=lane&15, row=4*(lane>>4)+b
  int rf = wr + ((lane >> 4) << 2);
  int cf = n0 + wc + (lane & 15);
#pragma unroll
  for (int m = 0; m < 4; m++) {
#pragma unroll
    for (int n = 0; n < 4; n++) {
#pragma unroll
      for (int b = 0; b < 4; b++) {
        int gr = m0 + rf + m * 16 + b;
        if (gr < n_e) {
          float c1 = acc1[m][n][b];
          float c2 = acc2[m][n][b];
          float h = c1 * c2 / (1.f + __expf(-c1));
          H[(size_t)(base + gr) * HID + cf + n * 16] = (bf16)h;
        }
      }
    }
  }
}

// ---------------- GEMM2: out[tok] += gate * (H @ Wc) ----------------
__launch_bounds__(256, 2)
__global__ void gemm2_k(const bf16* __restrict__ H, const bf16* __restrict__ wct,
                        const int* __restrict__ cnt, const int* __restrict__ eoff,
                        const int* __restrict__ rowtok, const float* __restrict__ rowgate,
                        float* __restrict__ out) {
  int e = blockIdx.z;
  int n_e = cnt[e];
  int m0 = blockIdx.y * BM;
  if (m0 >= n_e) return;
  int n0 = blockIdx.x * BN;
  int base = eoff[e];

  __shared__ __align__(16) bf16 sA[BM * LDT];
  __shared__ __align__(16) bf16 sB[BN * LDT];

  int tid = threadIdx.x;
  int lane = tid & 63;
  int wv = tid >> 6;
  int wr = (wv >> 1) << 6;
  int wc = (wv & 1) << 6;

  int srow = tid >> 2;
  int kc = (tid & 3) << 3;

  const bf16* ap[2];
#pragma unroll
  for (int p = 0; p < 2; p++) {
    int gi = base + m0 + srow + (p << 6);
    gi = gi < NSLOT ? gi : NSLOT - 1;
    ap[p] = H + (size_t)gi * HID + kc;
  }
  const bf16* bp = wct + ((size_t)e * EMB + n0 + srow) * HID + kc;

  f32x4 acc[4][4] = {};

  for (int k0 = 0; k0 < HID; k0 += BK) {
    uint4 a0 = *(const uint4*)(ap[0] + k0);
    uint4 a1 = *(const uint4*)(ap[1] + k0);
    uint4 b0 = *(const uint4*)(bp + k0);
    uint4 b1 = *(const uint4*)(bp + (size_t)64 * HID + k0);
    *(uint4*)&sA[srow * LDT + kc] = a0;
    *(uint4*)&sA[(srow + 64) * LDT + kc] = a1;
    *(uint4*)&sB[srow * LDT + kc] = b0;
    *(uint4*)&sB[(srow + 64) * LDT + kc] = b1;
    __syncthreads();

    bf16x8 af[4], bfr[4];
    int ra = (wr + (lane & 15)) * LDT + ((lane >> 4) << 3);
    int rb = (wc + (lane & 15)) * LDT + ((lane >> 4) << 3);
#pragma unroll
    for (int m = 0; m < 4; m++) af[m] = *(const bf16x8*)&sA[ra + m * 16 * LDT];
#pragma unroll
    for (int n = 0; n < 4; n++) bfr[n] = *(const bf16x8*)&sB[rb + n * 16 * LDT];
#pragma unroll
    for (int m = 0; m < 4; m++)
#pragma unroll
      for (int n = 0; n < 4; n++)
        acc[m][n] = __builtin_amdgcn_mfma_f32_16x16x32_bf16(af[m], bfr[n], acc[m][n], 0, 0, 0);
    __syncthreads();
  }

  int rf = wr + ((lane >> 4) << 2);
  int cf = n0 + wc + (lane & 15);
#pragma unroll
  for (int m = 0; m < 4; m++) {
#pragma unroll
    for (int b = 0; b < 4; b++) {
      int gr = m0 + rf + m * 16 + b;
      if (gr < n_e) {
        int idx = base + gr;
        int tok = rowtok[idx];
        float g = rowgate[idx];
        float* orow = out + (size_t)tok * EMB + cf;
#pragma unroll
        for (int n = 0; n < 4; n++)
          atomicAdd(orow + n * 16, g * acc[m][n][b]);
      }
    }
  }
}

extern "C" void kernel_launch(void* const* d_in, const int* in_sizes, int n_in,
                              void* d_out, int out_size, void* d_ws, size_t ws_size,
                              hipStream_t stream) {
  const float* x  = (const float*)d_in[0];
  const float* wg = (const float*)d_in[1];
  const float* w1 = (const float*)d_in[2];
  const float* w2 = (const float*)d_in[3];
  const float* wc = (const float*)d_in[4];
  float* out = (float*)d_out;

  const size_t WELEM = (size_t)NE * EMB * HID;
  bf16* w1t  = (bf16*)d_ws;                 // [E][HID][EMB] bf16 (W1^T per expert)
  bf16* w2t  = w1t + WELEM;                 // [E][HID][EMB]
  bf16* wct  = w2t + WELEM;                 // [E][EMB][HID] (Wc^T per expert)
  bf16* xb   = wct + WELEM;                 // [NTOK][EMB] bf16
  bf16* Hbuf = xb + (size_t)NTOK * EMB;     // [NSLOT][HID] bf16
  int* cnt    = (int*)(Hbuf + (size_t)NSLOT * HID);
  int* eoff   = cnt + 16;
  int* cursor = eoff + 16;
  int* tokexp = cursor + 16;                // [NSLOT]
  float* tokgate = (float*)(tokexp + NSLOT);
  int* rowtok    = (int*)(tokgate + NSLOT);
  float* rowgate = (float*)(rowtok + NSLOT);
  float* wgT     = rowgate + NSLOT;         // [16][1024] fp32, 64KB
  // total ws use: ~151.4 MB

  hipMemsetAsync(cnt, 0, 16 * sizeof(int), stream);
  hipMemsetAsync(out, 0, (size_t)out_size * sizeof(float), stream);

  dim3 tb(32, 8), tg(32, 32, NE);
  transpose_cvt<<<tg, tb, 0, stream>>>(w1, w1t);
  transpose_cvt<<<tg, tb, 0, stream>>>(w2, w2t);
  transpose_cvt<<<tg, tb, 0, stream>>>(wc, wct);
  wgT_k<<<64, 256, 0, stream>>>(wg, wgT);
  router_k<<<NTOK / 8, 512, 0, stream>>>(x, wgT, xb, tokexp, tokgate, cnt);
  scan_k<<<1, 64, 0, stream>>>(cnt, eoff, cursor);
  assign_k<<<NSLOT / 256, 256, 0, stream>>>(tokexp, tokgate, cursor, rowtok, rowgate);
  dim3 g1(HID / BN, NTOK / BM, NE);
  gemm1_k<<<g1, 256, 0, stream>>>(xb, w1t, w2t, cnt, eoff, rowtok, Hbuf);
  dim3 g2(EMB / BN, NTOK / BM, NE);
  gemm2_k<<<g2, 256, 0, stream>>>(Hbuf, wct, cnt, eoff, rowtok, rowgate, out);
}

// Round 3
// 344.125 us; speedup vs baseline: 1.7113x; 1.6249x over previous
//
#include <hip/hip_runtime.h>
#include <hip/hip_bf16.h>
#include <stdint.h>

#define EMB 1024
#define HID 1024
#define NE 16
#define NTOK 8192
#define NSLOT (NTOK * 2)
#define BM 128
#define BN 128
#define BK 32
#define LDT 40   // padded LDS row stride (bf16 elems): 80 B, breaks stride-64B bank conflict

typedef __bf16 bf16;
typedef __bf16 bf16x8 __attribute__((ext_vector_type(8)));
typedef __bf16 bf16x4 __attribute__((ext_vector_type(4)));
typedef float f32x4 __attribute__((ext_vector_type(4)));

// ---------------- weight transpose + fp32->bf16 ----------------
__global__ void transpose_cvt(const float* __restrict__ src, bf16* __restrict__ dst) {
  __shared__ float tile[32][33];
  int z = blockIdx.z;
  int x0 = blockIdx.x << 5, y0 = blockIdx.y << 5;
  const float* s = src + (size_t)z * EMB * HID;
  bf16* d = dst + (size_t)z * EMB * HID;
  int tx = threadIdx.x, ty = threadIdx.y;
#pragma unroll
  for (int i = 0; i < 32; i += 8)
    tile[ty + i][tx] = s[(size_t)(y0 + ty + i) * 1024 + x0 + tx];
  __syncthreads();
#pragma unroll
  for (int i = 0; i < 32; i += 8)
    d[(size_t)(x0 + ty + i) * 1024 + y0 + tx] = (bf16)tile[tx][ty + i];
}

// ---------------- w_gate [1024][16] -> wgT [16][1024] (fp32, 64KB, one-time) ----------
__global__ void wgT_k(const float* __restrict__ wg, float* __restrict__ wgT) {
  int f = blockIdx.x * 256 + threadIdx.x;   // 0..16383, coalesced read
  int d = f >> 4, e = f & 15;
  wgT[e * 1024 + d] = wg[f];
}

// ---------------- router: coalesced, LDS-staged wgT, fused x->bf16, NO atomics ------
// 1024 threads = 16 waves = 16 tokens per block. LDS: wgT 16x1024 fp32 = 64KB
// -> 2 blocks/CU = 32 waves/CU (full occupancy).
__launch_bounds__(1024)
__global__ void router_k(const float* __restrict__ x, const float* __restrict__ wgT,
                         bf16* __restrict__ xb,
                         int* __restrict__ tokexp, float* __restrict__ tokgate) {
  __shared__ float wgs[NE * 1024];
  for (int i = threadIdx.x; i < 4096; i += 1024)
    ((float4*)wgs)[i] = ((const float4*)wgT)[i];
  __syncthreads();

  int t = blockIdx.x * 16 + (threadIdx.x >> 6);
  int lane = threadIdx.x & 63;
  const float* xr = x + (size_t)t * EMB;

  float acc[NE];
#pragma unroll
  for (int e = 0; e < NE; e++) acc[e] = 0.f;

#pragma unroll
  for (int c = 0; c < 4; c++) {
    float4 xv = ((const float4*)xr)[c * 64 + lane];         // coalesced 16B/lane
    int dbase = c * 256 + lane * 4;
    bf16x4 o;                                               // fused fp32->bf16 store of x
    o[0] = (bf16)xv.x; o[1] = (bf16)xv.y; o[2] = (bf16)xv.z; o[3] = (bf16)xv.w;
    *(bf16x4*)(xb + (size_t)t * EMB + dbase) = o;
#pragma unroll
    for (int e = 0; e < NE; e++) {
      float4 wv = *(const float4*)&wgs[e * 1024 + dbase];   // ds_read_b128, conflict-free
      acc[e] += xv.x * wv.x + xv.y * wv.y + xv.z * wv.z + xv.w * wv.w;
    }
  }
#pragma unroll
  for (int e = 0; e < NE; e++) {
#pragma unroll
    for (int s = 32; s > 0; s >>= 1) acc[e] += __shfl_xor(acc[e], s);
  }
  if (lane == 0) {
    float m = acc[0];
#pragma unroll
    for (int e = 1; e < NE; e++) m = fmaxf(m, acc[e]);
    float p[NE]; float sum = 0.f;
#pragma unroll
    for (int e = 0; e < NE; e++) { p[e] = __expf(acc[e] - m); sum += p[e]; }
    float inv = 1.f / sum;
#pragma unroll
    for (int e = 0; e < NE; e++) p[e] *= inv;
    int i1 = 0;
#pragma unroll
    for (int e = 1; e < NE; e++) if (p[e] > p[i1]) i1 = e;   // first-occurrence max
    int i2 = (i1 == 0) ? 1 : 0;
#pragma unroll
    for (int e = 0; e < NE; e++) if (e != i1 && p[e] > p[i2]) i2 = e;
    tokexp[2 * t] = i1; tokexp[2 * t + 1] = i2;
    tokgate[2 * t] = p[i1]; tokgate[2 * t + 1] = p[i2];
  }
}

// ---------------- per-block expert histogram (LDS atomics only) ----------------
__global__ void hist_k(const int* __restrict__ tokexp, int* __restrict__ blockcnt) {
  __shared__ int h[NE];
  int tid = threadIdx.x;
  if (tid < NE) h[tid] = 0;
  __syncthreads();
  int e = tokexp[blockIdx.x * 256 + tid];
  atomicAdd(&h[e], 1);
  __syncthreads();
  if (tid < NE) blockcnt[blockIdx.x * NE + tid] = h[tid];
}

// ---------------- scan: per-expert totals, expert offsets, per-block offsets --------
__global__ void scan_k(const int* __restrict__ blockcnt, int* __restrict__ cnt,
                       int* __restrict__ eoff, int* __restrict__ blockoff) {
  __shared__ int scnt[NE], soff[NE];
  int t = threadIdx.x;   // 64 threads
  if (t < NE) {
    int s = 0;
    for (int b = 0; b < 64; b++) s += blockcnt[b * NE + t];
    scnt[t] = s;
    cnt[t] = s;
  }
  __syncthreads();
  if (t == 0) {
    int s = 0;
    for (int e = 0; e < NE; e++) { soff[e] = s; eoff[e] = s; s += scnt[e]; }
  }
  __syncthreads();
  if (t < NE) {
    int run = soff[t];
    for (int b = 0; b < 64; b++) { blockoff[b * NE + t] = run; run += blockcnt[b * NE + t]; }
  }
}

// ---------------- slot -> compact row, deterministic ballot ranking ----------------
__global__ void assign_k(const int* __restrict__ tokexp, const float* __restrict__ tokgate,
                         const int* __restrict__ blockoff, int* __restrict__ rowtok,
                         float* __restrict__ rowgate) {
  __shared__ int wavecnt[4][NE];
  __shared__ int waveoff[4][NE];
  int tid = threadIdx.x;
  int w = tid >> 6, lane = tid & 63;
  int s = blockIdx.x * 256 + tid;
  int e = tokexp[s];
  int rank = 0;
  unsigned long long ltmask = (1ull << lane) - 1ull;
#pragma unroll
  for (int ee = 0; ee < NE; ee++) {
    unsigned long long bal = __ballot(e == ee);
    if (e == ee) rank = __popcll(bal & ltmask);
    if (lane == ee) wavecnt[w][ee] = __popcll(bal);
  }
  __syncthreads();
  if (tid < 64) {
    int ww = tid >> 4, ee = tid & 15;
    int off = 0;
    for (int p = 0; p < ww; p++) off += wavecnt[p][ee];
    waveoff[ww][ee] = off;
  }
  __syncthreads();
  int pos = blockoff[blockIdx.x * NE + e] + waveoff[w][e] + rank;
  rowtok[pos] = s >> 1;
  rowgate[pos] = tokgate[s];
}

// ---------------- GEMM1: H = silu(X@W1) * (X@W2), gathered rows ----------------
__launch_bounds__(256, 2)
__global__ void gemm1_k(const bf16* __restrict__ xb, const bf16* __restrict__ w1t,
                        const bf16* __restrict__ w2t, const int* __restrict__ cnt,
                        const int* __restrict__ eoff, const int* __restrict__ rowtok,
                        bf16* __restrict__ H) {
  int e = blockIdx.z;
  int n_e = cnt[e];
  int m0 = blockIdx.y * BM;
  if (m0 >= n_e) return;
  int n0 = blockIdx.x * BN;
  int base = eoff[e];

  __shared__ __align__(16) bf16 sA[BM * LDT];
  __shared__ __align__(16) bf16 sB1[BN * LDT];
  __shared__ __align__(16) bf16 sB2[BN * LDT];

  int tid = threadIdx.x;
  int lane = tid & 63;
  int wv = tid >> 6;
  int wr = (wv >> 1) << 6;
  int wc = (wv & 1) << 6;

  int srow = tid >> 2;          // 0..63
  int kc = (tid & 3) << 3;      // 0,8,16,24 (bf16 elems)

  const bf16* aptr[2];
#pragma unroll
  for (int p = 0; p < 2; p++) {
    int gi = base + m0 + srow + (p << 6);
    gi = gi < NSLOT ? gi : NSLOT - 1;   // clamp: garbage rows never stored
    aptr[p] = xb + (size_t)rowtok[gi] * EMB + kc;
  }
  const bf16* b1p = w1t + ((size_t)e * HID + n0 + srow) * EMB + kc;
  const bf16* b2p = w2t + ((size_t)e * HID + n0 + srow) * EMB + kc;

  f32x4 acc1[4][4] = {};
  f32x4 acc2[4][4] = {};

  for (int k0 = 0; k0 < EMB; k0 += BK) {
    uint4 a0 = *(const uint4*)(aptr[0] + k0);
    uint4 a1 = *(const uint4*)(aptr[1] + k0);
    uint4 b10 = *(const uint4*)(b1p + k0);
    uint4 b11 = *(const uint4*)(b1p + (size_t)64 * EMB + k0);
    uint4 b20 = *(const uint4*)(b2p + k0);
    uint4 b21 = *(const uint4*)(b2p + (size_t)64 * EMB + k0);
    *(uint4*)&sA[srow * LDT + kc] = a0;
    *(uint4*)&sA[(srow + 64) * LDT + kc] = a1;
    *(uint4*)&sB1[srow * LDT + kc] = b10;
    *(uint4*)&sB1[(srow + 64) * LDT + kc] = b11;
    *(uint4*)&sB2[srow * LDT + kc] = b20;
    *(uint4*)&sB2[(srow + 64) * LDT + kc] = b21;
    __syncthreads();

    bf16x8 af[4], b1f[4], b2f[4];
    int ra = (wr + (lane & 15)) * LDT + ((lane >> 4) << 3);
    int rb = (wc + (lane & 15)) * LDT + ((lane >> 4) << 3);
#pragma unroll
    for (int m = 0; m < 4; m++) af[m] = *(const bf16x8*)&sA[ra + m * 16 * LDT];
#pragma unroll
    for (int n = 0; n < 4; n++) {
      b1f[n] = *(const bf16x8*)&sB1[rb + n * 16 * LDT];
      b2f[n] = *(const bf16x8*)&sB2[rb + n * 16 * LDT];
    }
#pragma unroll
    for (int m = 0; m < 4; m++)
#pragma unroll
      for (int n = 0; n < 4; n++) {
        acc1[m][n] = __builtin_amdgcn_mfma_f32_16x16x32_bf16(af[m], b1f[n], acc1[m][n], 0, 0, 0);
        acc2[m][n] = __builtin_amdgcn_mfma_f32_16x16x32_bf16(af[m], b2f[n], acc2[m][n], 0, 0, 0);
      }
    __syncthreads();
  }

  // epilogue: silu(c1)*c2 -> bf16 H.  D frag: col=lane&15, row=4*(lane>>4)+b
  int rf = wr + ((lane >> 4) << 2);
  int cf = n0 + wc + (lane & 15);
#pragma unroll
  for (int m = 0; m < 4; m++) {
#pragma unroll
    for (int n = 0; n < 4; n++) {
#pragma unroll
      for (int b = 0; b < 4; b++) {
        int gr = m0 + rf + m * 16 + b;
        if (gr < n_e) {
          float c1 = acc1[m][n][b];
          float c2 = acc2[m][n][b];
          float h = c1 * c2 / (1.f + __expf(-c1));
          H[(size_t)(base + gr) * HID + cf + n * 16] = (bf16)h;
        }
      }
    }
  }
}

// ---------------- GEMM2: out[tok] += gate * (H @ Wc) ----------------
__launch_bounds__(256, 2)
__global__ void gemm2_k(const bf16* __restrict__ H, const bf16* __restrict__ wct,
                        const int* __restrict__ cnt, const int* __restrict__ eoff,
                        const int* __restrict__ rowtok, const float* __restrict__ rowgate,
                        float* __restrict__ out) {
  int e = blockIdx.z;
  int n_e = cnt[e];
  int m0 = blockIdx.y * BM;
  if (m0 >= n_e) return;
  int n0 = blockIdx.x * BN;
  int base = eoff[e];

  __shared__ __align__(16) bf16 sA[BM * LDT];
  __shared__ __align__(16) bf16 sB[BN * LDT];

  int tid = threadIdx.x;
  int lane = tid & 63;
  int wv = tid >> 6;
  int wr = (wv >> 1) << 6;
  int wc = (wv & 1) << 6;

  int srow = tid >> 2;
  int kc = (tid & 3) << 3;

  const bf16* ap[2];
#pragma unroll
  for (int p = 0; p < 2; p++) {
    int gi = base + m0 + srow + (p << 6);
    gi = gi < NSLOT ? gi : NSLOT - 1;
    ap[p] = H + (size_t)gi * HID + kc;
  }
  const bf16* bp = wct + ((size_t)e * EMB + n0 + srow) * HID + kc;

  f32x4 acc[4][4] = {};

  for (int k0 = 0; k0 < HID; k0 += BK) {
    uint4 a0 = *(const uint4*)(ap[0] + k0);
    uint4 a1 = *(const uint4*)(ap[1] + k0);
    uint4 b0 = *(const uint4*)(bp + k0);
    uint4 b1 = *(const uint4*)(bp + (size_t)64 * HID + k0);
    *(uint4*)&sA[srow * LDT + kc] = a0;
    *(uint4*)&sA[(srow + 64) * LDT + kc] = a1;
    *(uint4*)&sB[srow * LDT + kc] = b0;
    *(uint4*)&sB[(srow + 64) * LDT + kc] = b1;
    __syncthreads();

    bf16x8 af[4], bfr[4];
    int ra = (wr + (lane & 15)) * LDT + ((lane >> 4) << 3);
    int rb = (wc + (lane & 15)) * LDT + ((lane >> 4) << 3);
#pragma unroll
    for (int m = 0; m < 4; m++) af[m] = *(const bf16x8*)&sA[ra + m * 16 * LDT];
#pragma unroll
    for (int n = 0; n < 4; n++) bfr[n] = *(const bf16x8*)&sB[rb + n * 16 * LDT];
#pragma unroll
    for (int m = 0; m < 4; m++)
#pragma unroll
      for (int n = 0; n < 4; n++)
        acc[m][n] = __builtin_amdgcn_mfma_f32_16x16x32_bf16(af[m], bfr[n], acc[m][n], 0, 0, 0);
    __syncthreads();
  }

  int rf = wr + ((lane >> 4) << 2);
  int cf = n0 + wc + (lane & 15);
#pragma unroll
  for (int m = 0; m < 4; m++) {
#pragma unroll
    for (int b = 0; b < 4; b++) {
      int gr = m0 + rf + m * 16 + b;
      if (gr < n_e) {
        int idx = base + gr;
        int tok = rowtok[idx];
        float g = rowgate[idx];
        float* orow = out + (size_t)tok * EMB + cf;
#pragma unroll
        for (int n = 0; n < 4; n++)
          atomicAdd(orow + n * 16, g * acc[m][n][b]);
      }
    }
  }
}

extern "C" void kernel_launch(void* const* d_in, const int* in_sizes, int n_in,
                              void* d_out, int out_size, void* d_ws, size_t ws_size,
                              hipStream_t stream) {
  const float* x  = (const float*)d_in[0];
  const float* wg = (const float*)d_in[1];
  const float* w1 = (const float*)d_in[2];
  const float* w2 = (const float*)d_in[3];
  const float* wc = (const float*)d_in[4];
  float* out = (float*)d_out;

  const size_t WELEM = (size_t)NE * EMB * HID;
  bf16* w1t  = (bf16*)d_ws;                 // [E][HID][EMB] bf16 (W1^T per expert)
  bf16* w2t  = w1t + WELEM;                 // [E][HID][EMB]
  bf16* wct  = w2t + WELEM;                 // [E][EMB][HID] (Wc^T per expert)
  bf16* xb   = wct + WELEM;                 // [NTOK][EMB] bf16
  bf16* Hbuf = xb + (size_t)NTOK * EMB;     // [NSLOT][HID] bf16
  int* cnt      = (int*)(Hbuf + (size_t)NSLOT * HID);
  int* eoff     = cnt + 16;
  int* blockcnt = eoff + 16;                // [64][16]
  int* blockoff = blockcnt + 64 * 16;       // [64][16]
  int* tokexp   = blockoff + 64 * 16;       // [NSLOT]
  float* tokgate = (float*)(tokexp + NSLOT);
  int* rowtok    = (int*)(tokgate + NSLOT);
  float* rowgate = (float*)(rowtok + NSLOT);
  float* wgT     = rowgate + NSLOT;         // [16][1024] fp32, 64KB
  // total ws use: ~145.5 MB

  hipMemsetAsync(out, 0, (size_t)out_size * sizeof(float), stream);

  dim3 tb(32, 8), tg(32, 32, NE);
  transpose_cvt<<<tg, tb, 0, stream>>>(w1, w1t);
  transpose_cvt<<<tg, tb, 0, stream>>>(w2, w2t);
  transpose_cvt<<<tg, tb, 0, stream>>>(wc, wct);
  wgT_k<<<64, 256, 0, stream>>>(wg, wgT);
  router_k<<<NTOK / 16, 1024, 0, stream>>>(x, wgT, xb, tokexp, tokgate);
  hist_k<<<NSLOT / 256, 256, 0, stream>>>(tokexp, blockcnt);
  scan_k<<<1, 64, 0, stream>>>(blockcnt, cnt, eoff, blockoff);
  assign_k<<<NSLOT / 256, 256, 0, stream>>>(tokexp, tokgate, blockoff, rowtok, rowgate);
  dim3 g1(HID / BN, NTOK / BM, NE);
  gemm1_k<<<g1, 256, 0, stream>>>(xb, w1t, w2t, cnt, eoff, rowtok, Hbuf);
  dim3 g2(EMB / BN, NTOK / BM, NE);
  gemm2_k<<<g2, 256, 0, stream>>>(Hbuf, wct, cnt, eoff, rowtok, rowgate, out);
}

// Round 4
// 308.930 us; speedup vs baseline: 1.9062x; 1.1139x over previous
//
#include <hip/hip_runtime.h>
#include <hip/hip_bf16.h>
#include <stdint.h>

#define EMB 1024
#define HID 1024
#define NE 16
#define NTOK 8192
#define NSLOT (NTOK * 2)
#define BM 128
#define BN 128
#define BK 32

typedef __bf16 bf16;
typedef __bf16 bf16x8 __attribute__((ext_vector_type(8)));
typedef __bf16 bf16x4 __attribute__((ext_vector_type(4)));
typedef float f32x4 __attribute__((ext_vector_type(4)));

// async global->LDS, 16B per lane; LDS dest must be wave-uniform base
#define GLOAD16(g, l)                                                        \
  __builtin_amdgcn_global_load_lds(                                          \
      (const __attribute__((address_space(1))) void*)(g),                    \
      (__attribute__((address_space(3))) void*)(l), 16, 0, 0)

// ---------------- fused weight transpose + fp32->bf16 (w1,w2,wc in one launch) -------
__global__ void transpose_cvt3(const float* __restrict__ w1, const float* __restrict__ w2,
                               const float* __restrict__ wcs, bf16* __restrict__ w1t,
                               bf16* __restrict__ w2t, bf16* __restrict__ wct) {
  __shared__ float tile[32][33];
  int zz = blockIdx.z;
  const float* s; bf16* d;
  if (zz < 16)      { s = w1;  d = w1t; }
  else if (zz < 32) { s = w2;  d = w2t; }
  else              { s = wcs; d = wct; }
  int z = zz & 15;
  int x0 = blockIdx.x << 5, y0 = blockIdx.y << 5;
  s += (size_t)z * EMB * HID;
  d += (size_t)z * EMB * HID;
  int tx = threadIdx.x, ty = threadIdx.y;
#pragma unroll
  for (int i = 0; i < 32; i += 8)
    tile[ty + i][tx] = s[(size_t)(y0 + ty + i) * 1024 + x0 + tx];
  __syncthreads();
#pragma unroll
  for (int i = 0; i < 32; i += 8)
    d[(size_t)(x0 + ty + i) * 1024 + y0 + tx] = (bf16)tile[tx][ty + i];
}

// ---------------- w_gate [1024][16] -> wgT [16][1024] (fp32, 64KB, one-time) ----------
__global__ void wgT_k(const float* __restrict__ wg, float* __restrict__ wgT) {
  int f = blockIdx.x * 256 + threadIdx.x;   // coalesced read
  int d = f >> 4, e = f & 15;
  wgT[e * 1024 + d] = wg[f];
}

// ---------------- router: coalesced, LDS-staged wgT, fused x->bf16, NO atomics ------
__launch_bounds__(1024)
__global__ void router_k(const float* __restrict__ x, const float* __restrict__ wgT,
                         bf16* __restrict__ xb,
                         int* __restrict__ tokexp, float* __restrict__ tokgate) {
  __shared__ float wgs[NE * 1024];
  for (int i = threadIdx.x; i < 4096; i += 1024)
    ((float4*)wgs)[i] = ((const float4*)wgT)[i];
  __syncthreads();

  int t = blockIdx.x * 16 + (threadIdx.x >> 6);
  int lane = threadIdx.x & 63;
  const float* xr = x + (size_t)t * EMB;

  float acc[NE];
#pragma unroll
  for (int e = 0; e < NE; e++) acc[e] = 0.f;

#pragma unroll
  for (int c = 0; c < 4; c++) {
    float4 xv = ((const float4*)xr)[c * 64 + lane];
    int dbase = c * 256 + lane * 4;
    bf16x4 o;
    o[0] = (bf16)xv.x; o[1] = (bf16)xv.y; o[2] = (bf16)xv.z; o[3] = (bf16)xv.w;
    *(bf16x4*)(xb + (size_t)t * EMB + dbase) = o;
#pragma unroll
    for (int e = 0; e < NE; e++) {
      float4 wv = *(const float4*)&wgs[e * 1024 + dbase];
      acc[e] += xv.x * wv.x + xv.y * wv.y + xv.z * wv.z + xv.w * wv.w;
    }
  }
#pragma unroll
  for (int e = 0; e < NE; e++) {
#pragma unroll
    for (int s = 32; s > 0; s >>= 1) acc[e] += __shfl_xor(acc[e], s);
  }
  if (lane == 0) {
    float m = acc[0];
#pragma unroll
    for (int e = 1; e < NE; e++) m = fmaxf(m, acc[e]);
    float p[NE]; float sum = 0.f;
#pragma unroll
    for (int e = 0; e < NE; e++) { p[e] = __expf(acc[e] - m); sum += p[e]; }
    float inv = 1.f / sum;
#pragma unroll
    for (int e = 0; e < NE; e++) p[e] *= inv;
    int i1 = 0;
#pragma unroll
    for (int e = 1; e < NE; e++) if (p[e] > p[i1]) i1 = e;
    int i2 = (i1 == 0) ? 1 : 0;
#pragma unroll
    for (int e = 0; e < NE; e++) if (e != i1 && p[e] > p[i2]) i2 = e;
    tokexp[2 * t] = i1; tokexp[2 * t + 1] = i2;
    tokgate[2 * t] = p[i1]; tokgate[2 * t + 1] = p[i2];
  }
}

// ---------------- per-block expert histogram (LDS atomics only) ----------------
__global__ void hist_k(const int* __restrict__ tokexp, int* __restrict__ blockcnt) {
  __shared__ int h[NE];
  int tid = threadIdx.x;
  if (tid < NE) h[tid] = 0;
  __syncthreads();
  int e = tokexp[blockIdx.x * 256 + tid];
  atomicAdd(&h[e], 1);
  __syncthreads();
  if (tid < NE) blockcnt[blockIdx.x * NE + tid] = h[tid];
}

// ---------------- scan: per-expert totals, expert offsets, per-block offsets --------
__global__ void scan_k(const int* __restrict__ blockcnt, int* __restrict__ cnt,
                       int* __restrict__ eoff, int* __restrict__ blockoff) {
  __shared__ int scnt[NE], soff[NE];
  int t = threadIdx.x;   // 64 threads
  if (t < NE) {
    int s = 0;
    for (int b = 0; b < 64; b++) s += blockcnt[b * NE + t];
    scnt[t] = s;
    cnt[t] = s;
  }
  __syncthreads();
  if (t == 0) {
    int s = 0;
    for (int e = 0; e < NE; e++) { soff[e] = s; eoff[e] = s; s += scnt[e]; }
  }
  __syncthreads();
  if (t < NE) {
    int run = soff[t];
    for (int b = 0; b < 64; b++) { blockoff[b * NE + t] = run; run += blockcnt[b * NE + t]; }
  }
}

// ---------------- slot -> compact row, deterministic ballot ranking ----------------
__global__ void assign_k(const int* __restrict__ tokexp, const float* __restrict__ tokgate,
                         const int* __restrict__ blockoff, int* __restrict__ rowtok,
                         float* __restrict__ rowgate) {
  __shared__ int wavecnt[4][NE];
  __shared__ int waveoff[4][NE];
  int tid = threadIdx.x;
  int w = tid >> 6, lane = tid & 63;
  int s = blockIdx.x * 256 + tid;
  int e = tokexp[s];
  int rank = 0;
  unsigned long long ltmask = (1ull << lane) - 1ull;
#pragma unroll
  for (int ee = 0; ee < NE; ee++) {
    unsigned long long bal = __ballot(e == ee);
    if (e == ee) rank = __popcll(bal & ltmask);
    if (lane == ee) wavecnt[w][ee] = __popcll(bal);
  }
  __syncthreads();
  if (tid < 64) {
    int ww = tid >> 4, ee = tid & 15;
    int off = 0;
    for (int p = 0; p < ww; p++) off += wavecnt[p][ee];
    waveoff[ww][ee] = off;
  }
  __syncthreads();
  int pos = blockoff[blockIdx.x * NE + e] + waveoff[w][e] + rank;
  rowtok[pos] = s >> 1;
  rowgate[pos] = tokgate[s];
}

// ---------------- GEMM1: H = silu(X@W1) * (X@W2), gathered rows, gload_lds ----------
// 1D grid 8192 blocks; XCD-chunk swizzle; LDS linear [128][32] bf16 per tile (8KB x3).
__launch_bounds__(256, 2)
__global__ void gemm1_k(const bf16* __restrict__ xb, const bf16* __restrict__ w1t,
                        const bf16* __restrict__ w2t, const int* __restrict__ cnt,
                        const int* __restrict__ eoff, const int* __restrict__ rowtok,
                        bf16* __restrict__ H) {
  int id = blockIdx.x;
  int nid = (id & 7) * 1024 + (id >> 3);      // XCD chunk: 2 experts per XCD
  int e = nid >> 9;
  int rem = nid & 511;
  int m0 = (rem >> 3) * BM;
  int n0 = (rem & 7) * BN;
  int n_e = cnt[e];
  if (m0 >= n_e) return;
  int base = eoff[e];

  __shared__ __align__(16) bf16 sA[BM * BK];
  __shared__ __align__(16) bf16 sB1[BN * BK];
  __shared__ __align__(16) bf16 sB2[BN * BK];

  int tid = threadIdx.x;
  int lane = tid & 63;
  int w = tid >> 6;
  int wr = (w >> 1) << 6;
  int wc = (w & 1) << 6;

  int srow = tid >> 2;          // 0..63
  int kc = (tid & 3) << 3;      // 0,8,16,24 (bf16 elems)

  // per-lane global row pointers (LDS layout is linear: load i covers rows i*64..i*64+63)
  const bf16* ag[2];
#pragma unroll
  for (int i = 0; i < 2; i++) {
    int gi = base + m0 + (i << 6) + srow;
    gi = gi < NSLOT ? gi : NSLOT - 1;         // clamp: garbage rows masked at store
    ag[i] = xb + (size_t)rowtok[gi] * EMB + kc;
  }
  const bf16* b1g = w1t + ((size_t)e * HID + n0 + srow) * EMB + kc;
  const bf16* b2g = w2t + ((size_t)e * HID + n0 + srow) * EMB + kc;

  char* lA = (char*)sA + w * 1024;
  char* lB1 = (char*)sB1 + w * 1024;
  char* lB2 = (char*)sB2 + w * 1024;

  f32x4 acc1[4][4] = {};
  f32x4 acc2[4][4] = {};

  int ra = (wr + (lane & 15)) * BK + ((lane >> 4) << 3);
  int rb = (wc + (lane & 15)) * BK + ((lane >> 4) << 3);

  for (int k0 = 0; k0 < EMB; k0 += BK) {
    GLOAD16(ag[0] + k0, lA);
    GLOAD16(ag[1] + k0, lA + 4096);
    GLOAD16(b1g + k0, lB1);
    GLOAD16(b1g + (size_t)64 * EMB + k0, lB1 + 4096);
    GLOAD16(b2g + k0, lB2);
    GLOAD16(b2g + (size_t)64 * EMB + k0, lB2 + 4096);
    __syncthreads();

    bf16x8 af[4], b1f[4], b2f[4];
#pragma unroll
    for (int m = 0; m < 4; m++) af[m] = *(const bf16x8*)&sA[ra + m * 16 * BK];
#pragma unroll
    for (int n = 0; n < 4; n++) {
      b1f[n] = *(const bf16x8*)&sB1[rb + n * 16 * BK];
      b2f[n] = *(const bf16x8*)&sB2[rb + n * 16 * BK];
    }
#pragma unroll
    for (int m = 0; m < 4; m++)
#pragma unroll
      for (int n = 0; n < 4; n++) {
        acc1[m][n] = __builtin_amdgcn_mfma_f32_16x16x32_bf16(af[m], b1f[n], acc1[m][n], 0, 0, 0);
        acc2[m][n] = __builtin_amdgcn_mfma_f32_16x16x32_bf16(af[m], b2f[n], acc2[m][n], 0, 0, 0);
      }
    __syncthreads();
  }

  // epilogue: silu(c1)*c2 -> bf16 H.  D frag: col=lane&15, row=4*(lane>>4)+b
  int rf = wr + ((lane >> 4) << 2);
  int cf = n0 + wc + (lane & 15);
#pragma unroll
  for (int m = 0; m < 4; m++) {
#pragma unroll
    for (int n = 0; n < 4; n++) {
#pragma unroll
      for (int b = 0; b < 4; b++) {
        int gr = m0 + rf + m * 16 + b;
        if (gr < n_e) {
          float c1 = acc1[m][n][b];
          float c2 = acc2[m][n][b];
          float h = c1 * c2 / (1.f + __expf(-c1));
          H[(size_t)(base + gr) * HID + cf + n * 16] = (bf16)h;
        }
      }
    }
  }
}

// ---------------- GEMM2: out[tok] += gate * (H @ Wc), gload_lds ----------------
__launch_bounds__(256, 2)
__global__ void gemm2_k(const bf16* __restrict__ H, const bf16* __restrict__ wct,
                        const int* __restrict__ cnt, const int* __restrict__ eoff,
                        const int* __restrict__ rowtok, const float* __restrict__ rowgate,
                        float* __restrict__ out) {
  int id = blockIdx.x;
  int nid = (id & 7) * 1024 + (id >> 3);
  int e = nid >> 9;
  int rem = nid & 511;
  int m0 = (rem >> 3) * BM;
  int n0 = (rem & 7) * BN;
  int n_e = cnt[e];
  if (m0 >= n_e) return;
  int base = eoff[e];

  __shared__ __align__(16) bf16 sA[BM * BK];
  __shared__ __align__(16) bf16 sB[BN * BK];

  int tid = threadIdx.x;
  int lane = tid & 63;
  int w = tid >> 6;
  int wr = (w >> 1) << 6;
  int wc = (w & 1) << 6;

  int srow = tid >> 2;
  int kc = (tid & 3) << 3;

  const bf16* ag[2];
#pragma unroll
  for (int i = 0; i < 2; i++) {
    int gi = base + m0 + (i << 6) + srow;     // H rows are slot-contiguous: no gather
    gi = gi < NSLOT ? gi : NSLOT - 1;
    ag[i] = H + (size_t)gi * HID + kc;
  }
  const bf16* bg = wct + ((size_t)e * EMB + n0 + srow) * HID + kc;

  char* lA = (char*)sA + w * 1024;
  char* lB = (char*)sB + w * 1024;

  f32x4 acc[4][4] = {};

  int ra = (wr + (lane & 15)) * BK + ((lane >> 4) << 3);
  int rb = (wc + (lane & 15)) * BK + ((lane >> 4) << 3);

  for (int k0 = 0; k0 < HID; k0 += BK) {
    GLOAD16(ag[0] + k0, lA);
    GLOAD16(ag[1] + k0, lA + 4096);
    GLOAD16(bg + k0, lB);
    GLOAD16(bg + (size_t)64 * HID + k0, lB + 4096);
    __syncthreads();

    bf16x8 af[4], bfr[4];
#pragma unroll
    for (int m = 0; m < 4; m++) af[m] = *(const bf16x8*)&sA[ra + m * 16 * BK];
#pragma unroll
    for (int n = 0; n < 4; n++) bfr[n] = *(const bf16x8*)&sB[rb + n * 16 * BK];
#pragma unroll
    for (int m = 0; m < 4; m++)
#pragma unroll
      for (int n = 0; n < 4; n++)
        acc[m][n] = __builtin_amdgcn_mfma_f32_16x16x32_bf16(af[m], bfr[n], acc[m][n], 0, 0, 0);
    __syncthreads();
  }

  int rf = wr + ((lane >> 4) << 2);
  int cf = n0 + wc + (lane & 15);
#pragma unroll
  for (int m = 0; m < 4; m++) {
#pragma unroll
    for (int b = 0; b < 4; b++) {
      int gr = m0 + rf + m * 16 + b;
      if (gr < n_e) {
        int idx = base + gr;
        int tok = rowtok[idx];
        float g = rowgate[idx];
        float* orow = out + (size_t)tok * EMB + cf;
#pragma unroll
        for (int n = 0; n < 4; n++)
          atomicAdd(orow + n * 16, g * acc[m][n][b]);
      }
    }
  }
}

extern "C" void kernel_launch(void* const* d_in, const int* in_sizes, int n_in,
                              void* d_out, int out_size, void* d_ws, size_t ws_size,
                              hipStream_t stream) {
  const float* x  = (const float*)d_in[0];
  const float* wg = (const float*)d_in[1];
  const float* w1 = (const float*)d_in[2];
  const float* w2 = (const float*)d_in[3];
  const float* wc = (const float*)d_in[4];
  float* out = (float*)d_out;

  const size_t WELEM = (size_t)NE * EMB * HID;
  bf16* w1t  = (bf16*)d_ws;                 // [E][HID][EMB] bf16 (W1^T per expert)
  bf16* w2t  = w1t + WELEM;                 // [E][HID][EMB]
  bf16* wct  = w2t + WELEM;                 // [E][EMB][HID] (Wc^T per expert)
  bf16* xb   = wct + WELEM;                 // [NTOK][EMB] bf16
  bf16* Hbuf = xb + (size_t)NTOK * EMB;     // [NSLOT][HID] bf16
  int* cnt      = (int*)(Hbuf + (size_t)NSLOT * HID);
  int* eoff     = cnt + 16;
  int* blockcnt = eoff + 16;                // [64][16]
  int* blockoff = blockcnt + 64 * 16;       // [64][16]
  int* tokexp   = blockoff + 64 * 16;       // [NSLOT]
  float* tokgate = (float*)(tokexp + NSLOT);
  int* rowtok    = (int*)(tokgate + NSLOT);
  float* rowgate = (float*)(rowtok + NSLOT);
  float* wgT     = rowgate + NSLOT;         // [16][1024] fp32, 64KB

  hipMemsetAsync(out, 0, (size_t)out_size * sizeof(float), stream);

  dim3 tb(32, 8), tg(32, 32, 48);
  transpose_cvt3<<<tg, tb, 0, stream>>>(w1, w2, wc, w1t, w2t, wct);
  wgT_k<<<64, 256, 0, stream>>>(wg, wgT);
  router_k<<<NTOK / 16, 1024, 0, stream>>>(x, wgT, xb, tokexp, tokgate);
  hist_k<<<NSLOT / 256, 256, 0, stream>>>(tokexp, blockcnt);
  scan_k<<<1, 64, 0, stream>>>(blockcnt, cnt, eoff, blockoff);
  assign_k<<<NSLOT / 256, 256, 0, stream>>>(tokexp, tokgate, blockoff, rowtok, rowgate);
  gemm1_k<<<8192, 256, 0, stream>>>(xb, w1t, w2t, cnt, eoff, rowtok, Hbuf);
  gemm2_k<<<8192, 256, 0, stream>>>(Hbuf, wct, cnt, eoff, rowtok, rowgate, out);
}

// Round 5
// 308.761 us; speedup vs baseline: 1.9073x; 1.0005x over previous
//
#include <hip/hip_runtime.h>
#include <hip/hip_bf16.h>
#include <stdint.h>

#define EMB 1024
#define HID 1024
#define NE 16
#define NTOK 8192
#define NSLOT (NTOK * 2)
#define BM 128
#define BN 128
#define BK 32

typedef __bf16 bf16;
typedef __bf16 bf16x8 __attribute__((ext_vector_type(8)));
typedef __bf16 bf16x4 __attribute__((ext_vector_type(4)));
typedef float f32x4 __attribute__((ext_vector_type(4)));

// async global->LDS, 16B per lane; LDS dest must be wave-uniform base
#define GLOAD16(g, l)                                                        \
  __builtin_amdgcn_global_load_lds(                                          \
      (const __attribute__((address_space(1))) void*)(g),                    \
      (__attribute__((address_space(3))) void*)(l), 16, 0, 0)

// ---------------- fused weight transpose + fp32->bf16 (w1,w2,wc in one launch) -------
__global__ void transpose_cvt3(const float* __restrict__ w1, const float* __restrict__ w2,
                               const float* __restrict__ wcs, bf16* __restrict__ w1t,
                               bf16* __restrict__ w2t, bf16* __restrict__ wct) {
  __shared__ float tile[32][33];
  int zz = blockIdx.z;
  const float* s; bf16* d;
  if (zz < 16)      { s = w1;  d = w1t; }
  else if (zz < 32) { s = w2;  d = w2t; }
  else              { s = wcs; d = wct; }
  int z = zz & 15;
  int x0 = blockIdx.x << 5, y0 = blockIdx.y << 5;
  s += (size_t)z * EMB * HID;
  d += (size_t)z * EMB * HID;
  int tx = threadIdx.x, ty = threadIdx.y;
#pragma unroll
  for (int i = 0; i < 32; i += 8)
    tile[ty + i][tx] = s[(size_t)(y0 + ty + i) * 1024 + x0 + tx];
  __syncthreads();
#pragma unroll
  for (int i = 0; i < 32; i += 8)
    d[(size_t)(x0 + ty + i) * 1024 + y0 + tx] = (bf16)tile[tx][ty + i];
}

// ---------------- w_gate [1024][16] -> wgT [16][1024] (fp32, 64KB, one-time) ----------
__global__ void wgT_k(const float* __restrict__ wg, float* __restrict__ wgT) {
  int f = blockIdx.x * 256 + threadIdx.x;   // coalesced read
  int d = f >> 4, e = f & 15;
  wgT[e * 1024 + d] = wg[f];
}

// ---------------- router: coalesced, LDS-staged wgT, fused x->bf16, NO atomics ------
__launch_bounds__(1024)
__global__ void router_k(const float* __restrict__ x, const float* __restrict__ wgT,
                         bf16* __restrict__ xb,
                         int* __restrict__ tokexp, float* __restrict__ tokgate) {
  __shared__ float wgs[NE * 1024];
  for (int i = threadIdx.x; i < 4096; i += 1024)
    ((float4*)wgs)[i] = ((const float4*)wgT)[i];
  __syncthreads();

  int t = blockIdx.x * 16 + (threadIdx.x >> 6);
  int lane = threadIdx.x & 63;
  const float* xr = x + (size_t)t * EMB;

  float acc[NE];
#pragma unroll
  for (int e = 0; e < NE; e++) acc[e] = 0.f;

#pragma unroll
  for (int c = 0; c < 4; c++) {
    float4 xv = ((const float4*)xr)[c * 64 + lane];
    int dbase = c * 256 + lane * 4;
    bf16x4 o;
    o[0] = (bf16)xv.x; o[1] = (bf16)xv.y; o[2] = (bf16)xv.z; o[3] = (bf16)xv.w;
    *(bf16x4*)(xb + (size_t)t * EMB + dbase) = o;
#pragma unroll
    for (int e = 0; e < NE; e++) {
      float4 wv = *(const float4*)&wgs[e * 1024 + dbase];
      acc[e] += xv.x * wv.x + xv.y * wv.y + xv.z * wv.z + xv.w * wv.w;
    }
  }
#pragma unroll
  for (int e = 0; e < NE; e++) {
#pragma unroll
    for (int s = 32; s > 0; s >>= 1) acc[e] += __shfl_xor(acc[e], s);
  }
  if (lane == 0) {
    float m = acc[0];
#pragma unroll
    for (int e = 1; e < NE; e++) m = fmaxf(m, acc[e]);
    float p[NE]; float sum = 0.f;
#pragma unroll
    for (int e = 0; e < NE; e++) { p[e] = __expf(acc[e] - m); sum += p[e]; }
    float inv = 1.f / sum;
#pragma unroll
    for (int e = 0; e < NE; e++) p[e] *= inv;
    int i1 = 0;
#pragma unroll
    for (int e = 1; e < NE; e++) if (p[e] > p[i1]) i1 = e;
    int i2 = (i1 == 0) ? 1 : 0;
#pragma unroll
    for (int e = 0; e < NE; e++) if (e != i1 && p[e] > p[i2]) i2 = e;
    tokexp[2 * t] = i1; tokexp[2 * t + 1] = i2;
    tokgate[2 * t] = p[i1]; tokgate[2 * t + 1] = p[i2];
  }
}

// ---------------- per-block expert histogram (LDS atomics only) ----------------
__global__ void hist_k(const int* __restrict__ tokexp, int* __restrict__ blockcnt) {
  __shared__ int h[NE];
  int tid = threadIdx.x;
  if (tid < NE) h[tid] = 0;
  __syncthreads();
  int e = tokexp[blockIdx.x * 256 + tid];
  atomicAdd(&h[e], 1);
  __syncthreads();
  if (tid < NE) blockcnt[blockIdx.x * NE + tid] = h[tid];
}

// ---------------- scan: per-expert totals, expert offsets, per-block offsets --------
__global__ void scan_k(const int* __restrict__ blockcnt, int* __restrict__ cnt,
                       int* __restrict__ eoff, int* __restrict__ blockoff) {
  __shared__ int scnt[NE], soff[NE];
  int t = threadIdx.x;   // 64 threads
  if (t < NE) {
    int s = 0;
    for (int b = 0; b < 64; b++) s += blockcnt[b * NE + t];
    scnt[t] = s;
    cnt[t] = s;
  }
  __syncthreads();
  if (t == 0) {
    int s = 0;
    for (int e = 0; e < NE; e++) { soff[e] = s; eoff[e] = s; s += scnt[e]; }
  }
  __syncthreads();
  if (t < NE) {
    int run = soff[t];
    for (int b = 0; b < 64; b++) { blockoff[b * NE + t] = run; run += blockcnt[b * NE + t]; }
  }
}

// ---------------- slot -> compact row, deterministic ballot ranking ----------------
__global__ void assign_k(const int* __restrict__ tokexp, const float* __restrict__ tokgate,
                         const int* __restrict__ blockoff, int* __restrict__ rowtok,
                         float* __restrict__ rowgate) {
  __shared__ int wavecnt[4][NE];
  __shared__ int waveoff[4][NE];
  int tid = threadIdx.x;
  int w = tid >> 6, lane = tid & 63;
  int s = blockIdx.x * 256 + tid;
  int e = tokexp[s];
  int rank = 0;
  unsigned long long ltmask = (1ull << lane) - 1ull;
#pragma unroll
  for (int ee = 0; ee < NE; ee++) {
    unsigned long long bal = __ballot(e == ee);
    if (e == ee) rank = __popcll(bal & ltmask);
    if (lane == ee) wavecnt[w][ee] = __popcll(bal);
  }
  __syncthreads();
  if (tid < 64) {
    int ww = tid >> 4, ee = tid & 15;
    int off = 0;
    for (int p = 0; p < ww; p++) off += wavecnt[p][ee];
    waveoff[ww][ee] = off;
  }
  __syncthreads();
  int pos = blockoff[blockIdx.x * NE + e] + waveoff[w][e] + rank;
  rowtok[pos] = s >> 1;
  rowgate[pos] = tokgate[s];
}

// ---------------- GEMM1: H = silu(X@W1) * (X@W2), dbuf + counted vmcnt ----------
__launch_bounds__(256, 2)
__global__ void gemm1_k(const bf16* __restrict__ xb, const bf16* __restrict__ w1t,
                        const bf16* __restrict__ w2t, const int* __restrict__ cnt,
                        const int* __restrict__ eoff, const int* __restrict__ rowtok,
                        bf16* __restrict__ H) {
  int id = blockIdx.x;
  int nid = (id & 7) * 1024 + (id >> 3);      // XCD chunk: 2 experts per XCD
  int e = nid >> 9;
  int rem = nid & 511;
  int m0 = (rem >> 3) * BM;
  int n0 = (rem & 7) * BN;
  int n_e = cnt[e];
  if (m0 >= n_e) return;
  int base = eoff[e];

  __shared__ __align__(16) bf16 sA[2][BM * BK];
  __shared__ __align__(16) bf16 sB1[2][BN * BK];
  __shared__ __align__(16) bf16 sB2[2][BN * BK];

  int tid = threadIdx.x;
  int lane = tid & 63;
  int w = tid >> 6;
  int wr = (w >> 1) << 6;
  int wc = (w & 1) << 6;

  int srow = tid >> 2;          // 0..63
  int kc = (tid & 3) << 3;      // 0,8,16,24 (bf16 elems)

  const bf16 *ag0, *ag1;
  {
    int gi0 = base + m0 + srow;
    int gi1 = base + m0 + 64 + srow;
    gi0 = gi0 < NSLOT ? gi0 : NSLOT - 1;      // clamp: garbage rows masked at store
    gi1 = gi1 < NSLOT ? gi1 : NSLOT - 1;
    ag0 = xb + (size_t)rowtok[gi0] * EMB + kc;
    ag1 = xb + (size_t)rowtok[gi1] * EMB + kc;
  }
  const bf16* b1g = w1t + ((size_t)e * HID + n0 + srow) * EMB + kc;
  const bf16* b2g = w2t + ((size_t)e * HID + n0 + srow) * EMB + kc;
  const size_t B64 = (size_t)64 * EMB;

  char* lA  = (char*)sA  + w * 1024;
  char* lB1 = (char*)sB1 + w * 1024;
  char* lB2 = (char*)sB2 + w * 1024;

#define G1STAGE(k0, b) do {                                                  \
    char* _A = lA + (b) * 8192; char* _B1 = lB1 + (b) * 8192;                \
    char* _B2 = lB2 + (b) * 8192;                                            \
    GLOAD16(ag0 + (k0), _A);                                                 \
    GLOAD16(ag1 + (k0), _A + 4096);                                          \
    GLOAD16(b1g + (k0), _B1);                                                \
    GLOAD16(b1g + B64 + (k0), _B1 + 4096);                                   \
    GLOAD16(b2g + (k0), _B2);                                                \
    GLOAD16(b2g + B64 + (k0), _B2 + 4096);                                   \
  } while (0)

  f32x4 acc1[4][4] = {};
  f32x4 acc2[4][4] = {};

  int ra = (wr + (lane & 15)) * BK + ((lane >> 4) << 3);
  int rb = (wc + (lane & 15)) * BK + ((lane >> 4) << 3);

  G1STAGE(0, 0);                               // prologue
  for (int t = 0; t < EMB / BK; t++) {
    int cur = t & 1;
    if (t < EMB / BK - 1) {
      G1STAGE((t + 1) * BK, cur ^ 1);          // keep next tile's 6 loads in flight
      asm volatile("s_waitcnt vmcnt(6)" ::: "memory");
    } else {
      asm volatile("s_waitcnt vmcnt(0)" ::: "memory");
    }
    __builtin_amdgcn_s_barrier();

    bf16x8 af[4], b1f[4], b2f[4];
#pragma unroll
    for (int m = 0; m < 4; m++) af[m] = *(const bf16x8*)&sA[cur][ra + m * 16 * BK];
#pragma unroll
    for (int n = 0; n < 4; n++) {
      b1f[n] = *(const bf16x8*)&sB1[cur][rb + n * 16 * BK];
      b2f[n] = *(const bf16x8*)&sB2[cur][rb + n * 16 * BK];
    }
#pragma unroll
    for (int m = 0; m < 4; m++)
#pragma unroll
      for (int n = 0; n < 4; n++) {
        acc1[m][n] = __builtin_amdgcn_mfma_f32_16x16x32_bf16(af[m], b1f[n], acc1[m][n], 0, 0, 0);
        acc2[m][n] = __builtin_amdgcn_mfma_f32_16x16x32_bf16(af[m], b2f[n], acc2[m][n], 0, 0, 0);
      }
    __builtin_amdgcn_s_barrier();
  }
#undef G1STAGE

  // epilogue: silu(c1)*c2 -> bf16 H.  D frag: col=lane&15, row=4*(lane>>4)+b
  int rf = wr + ((lane >> 4) << 2);
  int cf = n0 + wc + (lane & 15);
#pragma unroll
  for (int m = 0; m < 4; m++) {
#pragma unroll
    for (int n = 0; n < 4; n++) {
#pragma unroll
      for (int b = 0; b < 4; b++) {
        int gr = m0 + rf + m * 16 + b;
        if (gr < n_e) {
          float c1 = acc1[m][n][b];
          float c2 = acc2[m][n][b];
          float h = c1 * c2 / (1.f + __expf(-c1));
          H[(size_t)(base + gr) * HID + cf + n * 16] = (bf16)h;
        }
      }
    }
  }
}

// ---------------- GEMM2: out[tok] += gate * (H @ Wc), dbuf + counted vmcnt ----------
__launch_bounds__(256, 3)
__global__ void gemm2_k(const bf16* __restrict__ H, const bf16* __restrict__ wct,
                        const int* __restrict__ cnt, const int* __restrict__ eoff,
                        const int* __restrict__ rowtok, const float* __restrict__ rowgate,
                        float* __restrict__ out) {
  int id = blockIdx.x;
  int nid = (id & 7) * 1024 + (id >> 3);
  int e = nid >> 9;
  int rem = nid & 511;
  int m0 = (rem >> 3) * BM;
  int n0 = (rem & 7) * BN;
  int n_e = cnt[e];
  if (m0 >= n_e) return;
  int base = eoff[e];

  __shared__ __align__(16) bf16 sA[2][BM * BK];
  __shared__ __align__(16) bf16 sB[2][BN * BK];

  int tid = threadIdx.x;
  int lane = tid & 63;
  int w = tid >> 6;
  int wr = (w >> 1) << 6;
  int wc = (w & 1) << 6;

  int srow = tid >> 2;
  int kc = (tid & 3) << 3;

  const bf16 *ag0, *ag1;
  {
    int gi0 = base + m0 + srow;                // H rows are slot-contiguous: no gather
    int gi1 = base + m0 + 64 + srow;
    gi0 = gi0 < NSLOT ? gi0 : NSLOT - 1;
    gi1 = gi1 < NSLOT ? gi1 : NSLOT - 1;
    ag0 = H + (size_t)gi0 * HID + kc;
    ag1 = H + (size_t)gi1 * HID + kc;
  }
  const bf16* bg = wct + ((size_t)e * EMB + n0 + srow) * HID + kc;
  const size_t B64 = (size_t)64 * HID;

  char* lA = (char*)sA + w * 1024;
  char* lB = (char*)sB + w * 1024;

#define G2STAGE(k0, b) do {                                                  \
    char* _A = lA + (b) * 8192; char* _B = lB + (b) * 8192;                  \
    GLOAD16(ag0 + (k0), _A);                                                 \
    GLOAD16(ag1 + (k0), _A + 4096);                                          \
    GLOAD16(bg + (k0), _B);                                                  \
    GLOAD16(bg + B64 + (k0), _B + 4096);                                     \
  } while (0)

  f32x4 acc[4][4] = {};

  int ra = (wr + (lane & 15)) * BK + ((lane >> 4) << 3);
  int rb = (wc + (lane & 15)) * BK + ((lane >> 4) << 3);

  G2STAGE(0, 0);
  for (int t = 0; t < HID / BK; t++) {
    int cur = t & 1;
    if (t < HID / BK - 1) {
      G2STAGE((t + 1) * BK, cur ^ 1);
      asm volatile("s_waitcnt vmcnt(4)" ::: "memory");
    } else {
      asm volatile("s_waitcnt vmcnt(0)" ::: "memory");
    }
    __builtin_amdgcn_s_barrier();

    bf16x8 af[4], bfr[4];
#pragma unroll
    for (int m = 0; m < 4; m++) af[m] = *(const bf16x8*)&sA[cur][ra + m * 16 * BK];
#pragma unroll
    for (int n = 0; n < 4; n++) bfr[n] = *(const bf16x8*)&sB[cur][rb + n * 16 * BK];
#pragma unroll
    for (int m = 0; m < 4; m++)
#pragma unroll
      for (int n = 0; n < 4; n++)
        acc[m][n] = __builtin_amdgcn_mfma_f32_16x16x32_bf16(af[m], bfr[n], acc[m][n], 0, 0, 0);
    __builtin_amdgcn_s_barrier();
  }
#undef G2STAGE

  int rf = wr + ((lane >> 4) << 2);
  int cf = n0 + wc + (lane & 15);
#pragma unroll
  for (int m = 0; m < 4; m++) {
#pragma unroll
    for (int b = 0; b < 4; b++) {
      int gr = m0 + rf + m * 16 + b;
      if (gr < n_e) {
        int idx = base + gr;
        int tok = rowtok[idx];
        float g = rowgate[idx];
        float* orow = out + (size_t)tok * EMB + cf;
#pragma unroll
        for (int n = 0; n < 4; n++)
          atomicAdd(orow + n * 16, g * acc[m][n][b]);
      }
    }
  }
}

extern "C" void kernel_launch(void* const* d_in, const int* in_sizes, int n_in,
                              void* d_out, int out_size, void* d_ws, size_t ws_size,
                              hipStream_t stream) {
  const float* x  = (const float*)d_in[0];
  const float* wg = (const float*)d_in[1];
  const float* w1 = (const float*)d_in[2];
  const float* w2 = (const float*)d_in[3];
  const float* wc = (const float*)d_in[4];
  float* out = (float*)d_out;

  const size_t WELEM = (size_t)NE * EMB * HID;
  bf16* w1t  = (bf16*)d_ws;                 // [E][HID][EMB] bf16 (W1^T per expert)
  bf16* w2t  = w1t + WELEM;                 // [E][HID][EMB]
  bf16* wct  = w2t + WELEM;                 // [E][EMB][HID] (Wc^T per expert)
  bf16* xb   = wct + WELEM;                 // [NTOK][EMB] bf16
  bf16* Hbuf = xb + (size_t)NTOK * EMB;     // [NSLOT][HID] bf16
  int* cnt      = (int*)(Hbuf + (size_t)NSLOT * HID);
  int* eoff     = cnt + 16;
  int* blockcnt = eoff + 16;                // [64][16]
  int* blockoff = blockcnt + 64 * 16;       // [64][16]
  int* tokexp   = blockoff + 64 * 16;       // [NSLOT]
  float* tokgate = (float*)(tokexp + NSLOT);
  int* rowtok    = (int*)(tokgate + NSLOT);
  float* rowgate = (float*)(rowtok + NSLOT);
  float* wgT     = rowgate + NSLOT;         // [16][1024] fp32, 64KB

  hipMemsetAsync(out, 0, (size_t)out_size * sizeof(float), stream);

  dim3 tb(32, 8), tg(32, 32, 48);
  transpose_cvt3<<<tg, tb, 0, stream>>>(w1, w2, wc, w1t, w2t, wct);
  wgT_k<<<64, 256, 0, stream>>>(wg, wgT);
  router_k<<<NTOK / 16, 1024, 0, stream>>>(x, wgT, xb, tokexp, tokgate);
  hist_k<<<NSLOT / 256, 256, 0, stream>>>(tokexp, blockcnt);
  scan_k<<<1, 64, 0, stream>>>(blockcnt, cnt, eoff, blockoff);
  assign_k<<<NSLOT / 256, 256, 0, stream>>>(tokexp, tokgate, blockoff, rowtok, rowgate);
  gemm1_k<<<8192, 256, 0, stream>>>(xb, w1t, w2t, cnt, eoff, rowtok, Hbuf);
  gemm2_k<<<8192, 256, 0, stream>>>(Hbuf, wct, cnt, eoff, rowtok, rowgate, out);
}

// Round 6
// 302.856 us; speedup vs baseline: 1.9444x; 1.0195x over previous
//
#include <hip/hip_runtime.h>
#include <hip/hip_bf16.h>
#include <stdint.h>

#define EMB 1024
#define HID 1024
#define NE 16
#define NTOK 8192
#define NSLOT (NTOK * 2)
#define BM 128
#define BN 128
#define BK 32

typedef __bf16 bf16;
typedef __bf16 bf16x8 __attribute__((ext_vector_type(8)));
typedef __bf16 bf16x4 __attribute__((ext_vector_type(4)));
typedef float f32x4 __attribute__((ext_vector_type(4)));

// async global->LDS, 16B per lane; LDS dest must be wave-uniform base
#define GLOAD16(g, l)                                                        \
  __builtin_amdgcn_global_load_lds(                                          \
      (const __attribute__((address_space(1))) void*)(g),                    \
      (__attribute__((address_space(3))) void*)(l), 16, 0, 0)

// ---------------- vectorized weight transpose + fp32->bf16 (64x64 tiles) ------------
// src [1024 k][1024 n] fp32 -> dst [n][k] bf16.  float4 loads, bf16x8 stores.
__global__ void transpose_cvt3(const float* __restrict__ w1, const float* __restrict__ w2,
                               const float* __restrict__ wcs, bf16* __restrict__ w1t,
                               bf16* __restrict__ w2t, bf16* __restrict__ wct) {
  __shared__ bf16 tile[64][68];               // 68-elem pad: phase1/2 near-conflict-free
  int zz = blockIdx.z;
  const float* s; bf16* d;
  if (zz < 16)      { s = w1;  d = w1t; }
  else if (zz < 32) { s = w2;  d = w2t; }
  else              { s = wcs; d = wct; }
  int z = zz & 15;
  s += (size_t)z * EMB * HID;
  d += (size_t)z * EMB * HID;
  int k0 = blockIdx.y << 6, n0 = blockIdx.x << 6;
  int t = threadIdx.x;

  // phase 1: load 64x64 fp32 (float4/lane), convert, store row-major bf16 to LDS
  int r = t >> 4, c4 = t & 15;
#pragma unroll
  for (int i = 0; i < 4; i++) {
    int row = r + (i << 4);
    float4 v = *(const float4*)&s[(size_t)(k0 + row) * 1024 + n0 + (c4 << 2)];
    bf16x4 o;
    o[0] = (bf16)v.x; o[1] = (bf16)v.y; o[2] = (bf16)v.z; o[3] = (bf16)v.w;
    *(bf16x4*)&tile[row][c4 << 2] = o;
  }
  __syncthreads();

  // phase 2: gather 8 k-values per output chunk, store bf16x8 coalesced
  int r8 = t >> 3, ch = t & 7;
#pragma unroll
  for (int i = 0; i < 2; i++) {
    int on = r8 + (i << 5);                   // n within tile
    bf16x8 v;
#pragma unroll
    for (int j = 0; j < 8; j++) v[j] = tile[(ch << 3) + j][on];
    *(bf16x8*)&d[(size_t)(n0 + on) * 1024 + k0 + (ch << 3)] = v;
  }
}

// ---------------- w_gate [1024][16] -> wgT [16][1024] (fp32, 64KB, one-time) ----------
__global__ void wgT_k(const float* __restrict__ wg, float* __restrict__ wgT) {
  int f = blockIdx.x * 256 + threadIdx.x;   // coalesced read
  int d = f >> 4, e = f & 15;
  wgT[e * 1024 + d] = wg[f];
}

// ---------------- router: coalesced, LDS-staged wgT, fused x->bf16, NO atomics ------
__launch_bounds__(1024)
__global__ void router_k(const float* __restrict__ x, const float* __restrict__ wgT,
                         bf16* __restrict__ xb,
                         int* __restrict__ tokexp, float* __restrict__ tokgate) {
  __shared__ float wgs[NE * 1024];
  for (int i = threadIdx.x; i < 4096; i += 1024)
    ((float4*)wgs)[i] = ((const float4*)wgT)[i];
  __syncthreads();

  int t = blockIdx.x * 16 + (threadIdx.x >> 6);
  int lane = threadIdx.x & 63;
  const float* xr = x + (size_t)t * EMB;

  float acc[NE];
#pragma unroll
  for (int e = 0; e < NE; e++) acc[e] = 0.f;

#pragma unroll
  for (int c = 0; c < 4; c++) {
    float4 xv = ((const float4*)xr)[c * 64 + lane];
    int dbase = c * 256 + lane * 4;
    bf16x4 o;
    o[0] = (bf16)xv.x; o[1] = (bf16)xv.y; o[2] = (bf16)xv.z; o[3] = (bf16)xv.w;
    *(bf16x4*)(xb + (size_t)t * EMB + dbase) = o;
#pragma unroll
    for (int e = 0; e < NE; e++) {
      float4 wv = *(const float4*)&wgs[e * 1024 + dbase];
      acc[e] += xv.x * wv.x + xv.y * wv.y + xv.z * wv.z + xv.w * wv.w;
    }
  }
#pragma unroll
  for (int e = 0; e < NE; e++) {
#pragma unroll
    for (int s = 32; s > 0; s >>= 1) acc[e] += __shfl_xor(acc[e], s);
  }
  if (lane == 0) {
    float m = acc[0];
#pragma unroll
    for (int e = 1; e < NE; e++) m = fmaxf(m, acc[e]);
    float p[NE]; float sum = 0.f;
#pragma unroll
    for (int e = 0; e < NE; e++) { p[e] = __expf(acc[e] - m); sum += p[e]; }
    float inv = 1.f / sum;
#pragma unroll
    for (int e = 0; e < NE; e++) p[e] *= inv;
    int i1 = 0;
#pragma unroll
    for (int e = 1; e < NE; e++) if (p[e] > p[i1]) i1 = e;
    int i2 = (i1 == 0) ? 1 : 0;
#pragma unroll
    for (int e = 0; e < NE; e++) if (e != i1 && p[e] > p[i2]) i2 = e;
    tokexp[2 * t] = i1; tokexp[2 * t + 1] = i2;
    tokgate[2 * t] = p[i1]; tokgate[2 * t + 1] = p[i2];
  }
}

// ---------------- per-block expert histogram (LDS atomics only) ----------------
__global__ void hist_k(const int* __restrict__ tokexp, int* __restrict__ blockcnt) {
  __shared__ int h[NE];
  int tid = threadIdx.x;
  if (tid < NE) h[tid] = 0;
  __syncthreads();
  int e = tokexp[blockIdx.x * 256 + tid];
  atomicAdd(&h[e], 1);
  __syncthreads();
  if (tid < NE) blockcnt[blockIdx.x * NE + tid] = h[tid];
}

// ---------------- scan: per-expert totals, expert offsets, per-block offsets --------
__global__ void scan_k(const int* __restrict__ blockcnt, int* __restrict__ cnt,
                       int* __restrict__ eoff, int* __restrict__ blockoff) {
  __shared__ int scnt[NE], soff[NE];
  int t = threadIdx.x;   // 64 threads
  if (t < NE) {
    int s = 0;
    for (int b = 0; b < 64; b++) s += blockcnt[b * NE + t];
    scnt[t] = s;
    cnt[t] = s;
  }
  __syncthreads();
  if (t == 0) {
    int s = 0;
    for (int e = 0; e < NE; e++) { soff[e] = s; eoff[e] = s; s += scnt[e]; }
  }
  __syncthreads();
  if (t < NE) {
    int run = soff[t];
    for (int b = 0; b < 64; b++) { blockoff[b * NE + t] = run; run += blockcnt[b * NE + t]; }
  }
}

// ---------------- slot -> compact row, deterministic ballot ranking ----------------
__global__ void assign_k(const int* __restrict__ tokexp, const float* __restrict__ tokgate,
                         const int* __restrict__ blockoff, int* __restrict__ rowtok,
                         float* __restrict__ rowgate) {
  __shared__ int wavecnt[4][NE];
  __shared__ int waveoff[4][NE];
  int tid = threadIdx.x;
  int w = tid >> 6, lane = tid & 63;
  int s = blockIdx.x * 256 + tid;
  int e = tokexp[s];
  int rank = 0;
  unsigned long long ltmask = (1ull << lane) - 1ull;
#pragma unroll
  for (int ee = 0; ee < NE; ee++) {
    unsigned long long bal = __ballot(e == ee);
    if (e == ee) rank = __popcll(bal & ltmask);
    if (lane == ee) wavecnt[w][ee] = __popcll(bal);
  }
  __syncthreads();
  if (tid < 64) {
    int ww = tid >> 4, ee = tid & 15;
    int off = 0;
    for (int p = 0; p < ww; p++) off += wavecnt[p][ee];
    waveoff[ww][ee] = off;
  }
  __syncthreads();
  int pos = blockoff[blockIdx.x * NE + e] + waveoff[w][e] + rank;
  rowtok[pos] = s >> 1;
  rowgate[pos] = tokgate[s];
}

// LDS chunk swizzle: row stride is 64B = 4 chunks of 16B. Writer lane l (row=l>>2,
// chunk=l&3) fetches global k-chunk (l&3)^((l>>3)&3); reader XORs the same row bits.
// Spreads 16-lane row-groups over all 8 16B slots per 2 bank-rows -> 2-way (free).

// ---------------- GEMM1: H = silu(X@W1) * (X@W2), dbuf + counted vmcnt + swizzle ----
__launch_bounds__(256, 2)
__global__ void gemm1_k(const bf16* __restrict__ xb, const bf16* __restrict__ w1t,
                        const bf16* __restrict__ w2t, const int* __restrict__ cnt,
                        const int* __restrict__ eoff, const int* __restrict__ rowtok,
                        bf16* __restrict__ H) {
  int id = blockIdx.x;
  int nid = (id & 7) * 1024 + (id >> 3);      // XCD chunk: 2 experts per XCD
  int e = nid >> 9;
  int rem = nid & 511;
  int m0 = (rem >> 3) * BM;
  int n0 = (rem & 7) * BN;
  int n_e = cnt[e];
  if (m0 >= n_e) return;
  int base = eoff[e];

  __shared__ __align__(16) bf16 sA[2][BM * BK];
  __shared__ __align__(16) bf16 sB1[2][BN * BK];
  __shared__ __align__(16) bf16 sB2[2][BN * BK];

  int tid = threadIdx.x;
  int lane = tid & 63;
  int w = tid >> 6;
  int wr = (w >> 1) << 6;
  int wc = (w & 1) << 6;

  int srow = tid >> 2;                        // 0..63 (LDS row within 64-row group)
  int kc = (((tid & 3) ^ ((tid >> 3) & 3)) << 3);   // swizzled k-chunk (bf16 elems)

  const bf16 *ag0, *ag1;
  {
    int gi0 = base + m0 + srow;
    int gi1 = base + m0 + 64 + srow;
    gi0 = gi0 < NSLOT ? gi0 : NSLOT - 1;      // clamp: garbage rows masked at store
    gi1 = gi1 < NSLOT ? gi1 : NSLOT - 1;
    ag0 = xb + (size_t)rowtok[gi0] * EMB + kc;
    ag1 = xb + (size_t)rowtok[gi1] * EMB + kc;
  }
  const bf16* b1g = w1t + ((size_t)e * HID + n0 + srow) * EMB + kc;
  const bf16* b2g = w2t + ((size_t)e * HID + n0 + srow) * EMB + kc;
  const size_t B64 = (size_t)64 * EMB;

  char* lA  = (char*)sA  + w * 1024;
  char* lB1 = (char*)sB1 + w * 1024;
  char* lB2 = (char*)sB2 + w * 1024;

#define G1STAGE(k0, b) do {                                                  \
    char* _A = lA + (b) * 8192; char* _B1 = lB1 + (b) * 8192;                \
    char* _B2 = lB2 + (b) * 8192;                                            \
    GLOAD16(ag0 + (k0), _A);                                                 \
    GLOAD16(ag1 + (k0), _A + 4096);                                          \
    GLOAD16(b1g + (k0), _B1);                                                \
    GLOAD16(b1g + B64 + (k0), _B1 + 4096);                                   \
    GLOAD16(b2g + (k0), _B2);                                                \
    GLOAD16(b2g + B64 + (k0), _B2 + 4096);                                   \
  } while (0)

  f32x4 acc1[4][4] = {};
  f32x4 acc2[4][4] = {};

  // swizzled fragment read offsets (bf16 elems): row*32 + (k8 ^ rowbits12)*8
  int ch = ((lane >> 4) ^ ((lane >> 1) & 3)) << 3;
  int ra = (wr + (lane & 15)) * BK + ch;
  int rb = (wc + (lane & 15)) * BK + ch;

  G1STAGE(0, 0);                               // prologue
  for (int t = 0; t < EMB / BK; t++) {
    int cur = t & 1;
    if (t < EMB / BK - 1) {
      G1STAGE((t + 1) * BK, cur ^ 1);          // keep next tile's 6 loads in flight
      asm volatile("s_waitcnt vmcnt(6)" ::: "memory");
    } else {
      asm volatile("s_waitcnt vmcnt(0)" ::: "memory");
    }
    __builtin_amdgcn_s_barrier();

    bf16x8 af[4], b1f[4], b2f[4];
#pragma unroll
    for (int m = 0; m < 4; m++) af[m] = *(const bf16x8*)&sA[cur][ra + m * 16 * BK];
#pragma unroll
    for (int n = 0; n < 4; n++) {
      b1f[n] = *(const bf16x8*)&sB1[cur][rb + n * 16 * BK];
      b2f[n] = *(const bf16x8*)&sB2[cur][rb + n * 16 * BK];
    }
#pragma unroll
    for (int m = 0; m < 4; m++)
#pragma unroll
      for (int n = 0; n < 4; n++) {
        acc1[m][n] = __builtin_amdgcn_mfma_f32_16x16x32_bf16(af[m], b1f[n], acc1[m][n], 0, 0, 0);
        acc2[m][n] = __builtin_amdgcn_mfma_f32_16x16x32_bf16(af[m], b2f[n], acc2[m][n], 0, 0, 0);
      }
    __builtin_amdgcn_s_barrier();
  }
#undef G1STAGE

  // epilogue: silu(c1)*c2 -> bf16 H.  D frag: col=lane&15, row=4*(lane>>4)+b
  int rf = wr + ((lane >> 4) << 2);
  int cf = n0 + wc + (lane & 15);
#pragma unroll
  for (int m = 0; m < 4; m++) {
#pragma unroll
    for (int n = 0; n < 4; n++) {
#pragma unroll
      for (int b = 0; b < 4; b++) {
        int gr = m0 + rf + m * 16 + b;
        if (gr < n_e) {
          float c1 = acc1[m][n][b];
          float c2 = acc2[m][n][b];
          float h = c1 * c2 / (1.f + __expf(-c1));
          H[(size_t)(base + gr) * HID + cf + n * 16] = (bf16)h;
        }
      }
    }
  }
}

// ---------------- GEMM2: out[tok] += gate * (H @ Wc), dbuf + vmcnt + swizzle ---------
__launch_bounds__(256, 3)
__global__ void gemm2_k(const bf16* __restrict__ H, const bf16* __restrict__ wct,
                        const int* __restrict__ cnt, const int* __restrict__ eoff,
                        const int* __restrict__ rowtok, const float* __restrict__ rowgate,
                        float* __restrict__ out) {
  int id = blockIdx.x;
  int nid = (id & 7) * 1024 + (id >> 3);
  int e = nid >> 9;
  int rem = nid & 511;
  int m0 = (rem >> 3) * BM;
  int n0 = (rem & 7) * BN;
  int n_e = cnt[e];
  if (m0 >= n_e) return;
  int base = eoff[e];

  __shared__ __align__(16) bf16 sA[2][BM * BK];
  __shared__ __align__(16) bf16 sB[2][BN * BK];

  int tid = threadIdx.x;
  int lane = tid & 63;
  int w = tid >> 6;
  int wr = (w >> 1) << 6;
  int wc = (w & 1) << 6;

  int srow = tid >> 2;
  int kc = (((tid & 3) ^ ((tid >> 3) & 3)) << 3);

  const bf16 *ag0, *ag1;
  {
    int gi0 = base + m0 + srow;                // H rows are slot-contiguous: no gather
    int gi1 = base + m0 + 64 + srow;
    gi0 = gi0 < NSLOT ? gi0 : NSLOT - 1;
    gi1 = gi1 < NSLOT ? gi1 : NSLOT - 1;
    ag0 = H + (size_t)gi0 * HID + kc;
    ag1 = H + (size_t)gi1 * HID + kc;
  }
  const bf16* bg = wct + ((size_t)e * EMB + n0 + srow) * HID + kc;
  const size_t B64 = (size_t)64 * HID;

  char* lA = (char*)sA + w * 1024;
  char* lB = (char*)sB + w * 1024;

#define G2STAGE(k0, b) do {                                                  \
    char* _A = lA + (b) * 8192; char* _B = lB + (b) * 8192;                  \
    GLOAD16(ag0 + (k0), _A);                                                 \
    GLOAD16(ag1 + (k0), _A + 4096);                                          \
    GLOAD16(bg + (k0), _B);                                                  \
    GLOAD16(bg + B64 + (k0), _B + 4096);                                     \
  } while (0)

  f32x4 acc[4][4] = {};

  int ch = ((lane >> 4) ^ ((lane >> 1) & 3)) << 3;
  int ra = (wr + (lane & 15)) * BK + ch;
  int rb = (wc + (lane & 15)) * BK + ch;

  G2STAGE(0, 0);
  for (int t = 0; t < HID / BK; t++) {
    int cur = t & 1;
    if (t < HID / BK - 1) {
      G2STAGE((t + 1) * BK, cur ^ 1);
      asm volatile("s_waitcnt vmcnt(4)" ::: "memory");
    } else {
      asm volatile("s_waitcnt vmcnt(0)" ::: "memory");
    }
    __builtin_amdgcn_s_barrier();

    bf16x8 af[4], bfr[4];
#pragma unroll
    for (int m = 0; m < 4; m++) af[m] = *(const bf16x8*)&sA[cur][ra + m * 16 * BK];
#pragma unroll
    for (int n = 0; n < 4; n++) bfr[n] = *(const bf16x8*)&sB[cur][rb + n * 16 * BK];
#pragma unroll
    for (int m = 0; m < 4; m++)
#pragma unroll
      for (int n = 0; n < 4; n++)
        acc[m][n] = __builtin_amdgcn_mfma_f32_16x16x32_bf16(af[m], bfr[n], acc[m][n], 0, 0, 0);
    __builtin_amdgcn_s_barrier();
  }
#undef G2STAGE

  int rf = wr + ((lane >> 4) << 2);
  int cf = n0 + wc + (lane & 15);
#pragma unroll
  for (int m = 0; m < 4; m++) {
#pragma unroll
    for (int b = 0; b < 4; b++) {
      int gr = m0 + rf + m * 16 + b;
      if (gr < n_e) {
        int idx = base + gr;
        int tok = rowtok[idx];
        float g = rowgate[idx];
        float* orow = out + (size_t)tok * EMB + cf;
#pragma unroll
        for (int n = 0; n < 4; n++)
          atomicAdd(orow + n * 16, g * acc[m][n][b]);
      }
    }
  }
}

extern "C" void kernel_launch(void* const* d_in, const int* in_sizes, int n_in,
                              void* d_out, int out_size, void* d_ws, size_t ws_size,
                              hipStream_t stream) {
  const float* x  = (const float*)d_in[0];
  const float* wg = (const float*)d_in[1];
  const float* w1 = (const float*)d_in[2];
  const float* w2 = (const float*)d_in[3];
  const float* wc = (const float*)d_in[4];
  float* out = (float*)d_out;

  const size_t WELEM = (size_t)NE * EMB * HID;
  bf16* w1t  = (bf16*)d_ws;                 // [E][HID][EMB] bf16 (W1^T per expert)
  bf16* w2t  = w1t + WELEM;                 // [E][HID][EMB]
  bf16* wct  = w2t + WELEM;                 // [E][EMB][HID] (Wc^T per expert)
  bf16* xb   = wct + WELEM;                 // [NTOK][EMB] bf16
  bf16* Hbuf = xb + (size_t)NTOK * EMB;     // [NSLOT][HID] bf16
  int* cnt      = (int*)(Hbuf + (size_t)NSLOT * HID);
  int* eoff     = cnt + 16;
  int* blockcnt = eoff + 16;                // [64][16]
  int* blockoff = blockcnt + 64 * 16;       // [64][16]
  int* tokexp   = blockoff + 64 * 16;       // [NSLOT]
  float* tokgate = (float*)(tokexp + NSLOT);
  int* rowtok    = (int*)(tokgate + NSLOT);
  float* rowgate = (float*)(rowtok + NSLOT);
  float* wgT     = rowgate + NSLOT;         // [16][1024] fp32, 64KB

  hipMemsetAsync(out, 0, (size_t)out_size * sizeof(float), stream);

  dim3 tg(16, 16, 48);
  transpose_cvt3<<<tg, 256, 0, stream>>>(w1, w2, wc, w1t, w2t, wct);
  wgT_k<<<64, 256, 0, stream>>>(wg, wgT);
  router_k<<<NTOK / 16, 1024, 0, stream>>>(x, wgT, xb, tokexp, tokgate);
  hist_k<<<NSLOT / 256, 256, 0, stream>>>(tokexp, blockcnt);
  scan_k<<<1, 64, 0, stream>>>(blockcnt, cnt, eoff, blockoff);
  assign_k<<<NSLOT / 256, 256, 0, stream>>>(tokexp, tokgate, blockoff, rowtok, rowgate);
  gemm1_k<<<8192, 256, 0, stream>>>(xb, w1t, w2t, cnt, eoff, rowtok, Hbuf);
  gemm2_k<<<8192, 256, 0, stream>>>(Hbuf, wct, cnt, eoff, rowtok, rowgate, out);
}